// Round 9
// baseline (1039.689 us; speedup 1.0000x reference)
//
#include <hip/hip_runtime.h>
#include <hip/hip_bf16.h>

#define CC 64
#define HIDN 128
#define DCC 16
#define HH 128
#define WW 128
#define HWS (HH*WW)        // 16384
#define BB 16
#define NPIX (BB*HWS)      // 262144

typedef __hip_bfloat16 bf16;
typedef __attribute__((ext_vector_type(8))) unsigned short ushort8;
typedef __attribute__((ext_vector_type(4))) unsigned short ushort4v;
typedef __attribute__((ext_vector_type(4))) float float4v;
typedef __attribute__((ext_vector_type(8))) short bf16x8;
typedef __attribute__((ext_vector_type(4))) float f32x4;

__device__ __forceinline__ float rcp_fast(float x){ return __builtin_amdgcn_rcpf(x); }
__device__ __forceinline__ float ftanh(float x){
    float e = __expf(2.f*x);
    return 1.f - 2.f*rcp_fast(e + 1.f);
}
__device__ __forceinline__ float fsig(float x){
    return rcp_fast(1.f + __expf(-x));
}
__device__ __forceinline__ float fgelu(float x){
    return x * fsig(x*(1.5957691216f + 0.07135481283f*x*x));
}
__device__ __forceinline__ float b2f(bf16 v){ return __bfloat162float(v); }
__device__ __forceinline__ bf16  f2b(float v){ return __float2bfloat16(v); }
__device__ __forceinline__ float u2f(unsigned short u){
    unsigned v = ((unsigned)u) << 16; return __uint_as_float(v);
}
__device__ __forceinline__ unsigned short f2u(float f){
    bf16 h = __float2bfloat16(f);
    return *reinterpret_cast<unsigned short*>(&h);
}
__device__ __forceinline__ bf16x8 packf(float4v a, float4v b){
    bf16x8 r;
    r[0]=(short)f2u(a.x); r[1]=(short)f2u(a.y); r[2]=(short)f2u(a.z); r[3]=(short)f2u(a.w);
    r[4]=(short)f2u(b.x); r[5]=(short)f2u(b.y); r[6]=(short)f2u(b.z); r[7]=(short)f2u(b.w);
    return r;
}
// h1b row-XOR swizzle: 8-px granular, keeps ushort8 blocks contiguous,
// spreads copy-out column reads across banks (2-way = free).
__device__ __forceinline__ int lidx(int row, int pxc){
    return row*128 + (pxc ^ ((row&15)<<3));
}

// ---------------------------------------------------------------- gate (MFMA, LDS-staged x, zero-shuffle chain)
// F32=1: read float input directly (layer 0) — replaces k_convert.
template<int F32>
__global__ __launch_bounds__(256,2) void k_gate(
    const float* __restrict__ xf, const bf16* __restrict__ xb,
    const float* __restrict__ wz1, const float* __restrict__ bz1,
    const float* __restrict__ wz2, const float* __restrict__ bz2,
    const float* __restrict__ wf1, const float* __restrict__ bf1,
    const float* __restrict__ wf2, const float* __restrict__ bf2,
    bf16* __restrict__ vout)
{
    __shared__ __align__(16) unsigned short xs[512*64];   // [px][ch] swizzled, 64 KB
    const int t = threadIdx.x;
    const int lane = t & 63;
    const int wv = t >> 6;
    const int col = lane & 15;
    const int g = lane >> 4;
    const int blk = blockIdx.x;
    const int b = blk >> 5;
    const int sp0 = (blk & 31) << 9;

    // ---- stage x: 64 ch x 512 px, coalesced loads, transposed+swizzled store
    {
        const int ch = t & 63;
        const int wg = t >> 6;
        const size_t base = ((size_t)b*CC + ch)*HWS + sp0;
        #pragma unroll
        for (int i=0;i<16;++i){
            int bufpx = (wg*16 + i) << 3;
            ushort8 val;
            if (F32){
                float4v a = *reinterpret_cast<const float4v*>(xf + base + bufpx);
                float4v c = *reinterpret_cast<const float4v*>(xf + base + bufpx + 4);
                val[0]=f2u(a.x); val[1]=f2u(a.y); val[2]=f2u(a.z); val[3]=f2u(a.w);
                val[4]=f2u(c.x); val[5]=f2u(c.y); val[6]=f2u(c.z); val[7]=f2u(c.w);
            } else {
                val = *reinterpret_cast<const ushort8*>(xb + base + bufpx);
            }
            #pragma unroll
            for (int j=0;j<8;++j){
                int px = bufpx + j;
                *(unsigned short*)((char*)xs + px*128 + ((ch*2) ^ ((px&7)<<4))) = val[j];
            }
        }
    }

    bf16x8 Az1[4][2], Af1[4][2], Az2[4][2], Af2[4][2];
    #pragma unroll
    for (int ot=0; ot<4; ++ot){
        #pragma unroll
        for (int kh=0; kh<2; ++kh){
            const float* p;
            p = wz1 + (ot*16+col)*64 + kh*32 + g*8;
            Az1[ot][kh] = packf(*(const float4v*)p, *(const float4v*)(p+4));
            p = wf1 + (ot*16+col)*64 + kh*32 + g*8;
            Af1[ot][kh] = packf(*(const float4v*)p, *(const float4v*)(p+4));
            p = wz2 + (ot*16+col)*64 + kh*32 + g*4;
            Az2[ot][kh] = packf(*(const float4v*)p, *(const float4v*)(p+16));
            p = wf2 + (ot*16+col)*64 + kh*32 + g*4;
            Af2[ot][kh] = packf(*(const float4v*)p, *(const float4v*)(p+16));
        }
    }
    __syncthreads();

    bf16* vb = vout + (size_t)b*CC*HWS;

    for (int it = wv; it < 32; it += 4){
        const int lpx = it*16 + col;
        const int px = sp0 + lpx;
        bf16x8 Bx[2];
        Bx[0] = *(const bf16x8*)((char*)xs + lpx*128 + ((g*16) ^ ((lpx&7)<<4)));
        Bx[1] = *(const bf16x8*)((char*)xs + lpx*128 + ((64 + g*16) ^ ((lpx&7)<<4)));
        f32x4 Dz[4], Df[4];
        #pragma unroll
        for (int ot=0; ot<4; ++ot){
            Dz[ot] = *(const f32x4*)(bz1 + ot*16 + g*4);
            Df[ot] = *(const f32x4*)(bf1 + ot*16 + g*4);
        }
        #pragma unroll
        for (int kh=0; kh<2; ++kh)
            #pragma unroll
            for (int ot=0; ot<4; ++ot){
                Dz[ot] = __builtin_amdgcn_mfma_f32_16x16x32_bf16(Az1[ot][kh], Bx[kh], Dz[ot], 0,0,0);
                Df[ot] = __builtin_amdgcn_mfma_f32_16x16x32_bf16(Af1[ot][kh], Bx[kh], Df[ot], 0,0,0);
            }
        #pragma unroll
        for (int ot=0; ot<4; ++ot)
            #pragma unroll
            for (int r=0; r<4; ++r){
                Dz[ot][r] = ftanh(Dz[ot][r]);
                Df[ot][r] = ftanh(Df[ot][r]);
            }
        bf16x8 Bz[2], Bf[2];
        #pragma unroll
        for (int kh=0; kh<2; ++kh)
            #pragma unroll
            for (int j=0; j<4; ++j){
                Bz[kh][j]   = (short)f2u(Dz[2*kh][j]);
                Bz[kh][4+j] = (short)f2u(Dz[2*kh+1][j]);
                Bf[kh][j]   = (short)f2u(Df[2*kh][j]);
                Bf[kh][4+j] = (short)f2u(Df[2*kh+1][j]);
            }
        f32x4 Ez[4], Ef[4];
        #pragma unroll
        for (int ot=0; ot<4; ++ot){
            Ez[ot] = *(const f32x4*)(bz2 + ot*16 + g*4);
            Ef[ot] = *(const f32x4*)(bf2 + ot*16 + g*4);
        }
        #pragma unroll
        for (int kh=0; kh<2; ++kh)
            #pragma unroll
            for (int ot=0; ot<4; ++ot){
                Ez[ot] = __builtin_amdgcn_mfma_f32_16x16x32_bf16(Az2[ot][kh], Bz[kh], Ez[ot], 0,0,0);
                Ef[ot] = __builtin_amdgcn_mfma_f32_16x16x32_bf16(Af2[ot][kh], Bf[kh], Ef[ot], 0,0,0);
            }
        #pragma unroll
        for (int ot=0; ot<4; ++ot)
            #pragma unroll
            for (int r=0; r<4; ++r){
                float Zv = ftanh(Ez[ot][r]);
                float Fv = fsig(Ef[ot][r]);
                *reinterpret_cast<unsigned short*>(vb + (size_t)(ot*16+g*4+r)*HWS + px)
                    = f2u((1.f - Fv)*Zv);
            }
    }
}

// ---------------------------------------------------------------- pconv (16->16, 3x3), 4 px/thread
__global__ __launch_bounds__(256) void k_pconv(
    const bf16* __restrict__ v, const float* __restrict__ w, bf16* __restrict__ x1)
{
    int gid = blockIdx.x*256 + threadIdx.x;
    int b = gid >> 12;
    int sp4 = (gid & 4095) << 2;
    int y = sp4 >> 7, x0 = sp4 & 127;
    const bf16* vb = v + (size_t)b*CC*HWS;
    float acc[DCC][4];
    #pragma unroll
    for (int o=0;o<DCC;++o)
        #pragma unroll
        for (int i=0;i<4;++i) acc[o][i] = 0.f;

    #pragma unroll 1
    for (int ic=0; ic<DCC; ++ic){
        const bf16* ip = vb + (size_t)ic*HWS;
        float xv[3][6];
        #pragma unroll
        for (int ky=0;ky<3;++ky){
            int yy = y + ky - 1;
            if (yy >= 0 && yy < HH){
                const bf16* rp = ip + yy*WW + x0;
                ushort4v mv = *reinterpret_cast<const ushort4v*>(rp);
                xv[ky][1]=u2f(mv[0]); xv[ky][2]=u2f(mv[1]);
                xv[ky][3]=u2f(mv[2]); xv[ky][4]=u2f(mv[3]);
                xv[ky][0] = (x0>0)     ? b2f(rp[-1]) : 0.f;
                xv[ky][5] = (x0+4<WW)  ? b2f(rp[4])  : 0.f;
            } else {
                #pragma unroll
                for (int i=0;i<6;++i) xv[ky][i] = 0.f;
            }
        }
        #pragma unroll
        for (int o=0;o<DCC;++o){
            const float* wp = w + (size_t)(o*DCC+ic)*9;
            #pragma unroll
            for (int ky=0;ky<3;++ky){
                float w0 = wp[ky*3+0], w1 = wp[ky*3+1], w2 = wp[ky*3+2];
                #pragma unroll
                for (int i=0;i<4;++i)
                    acc[o][i] = fmaf(w0, xv[ky][i],
                                fmaf(w1, xv[ky][i+1],
                                fmaf(w2, xv[ky][i+2], acc[o][i])));
            }
        }
    }
    bf16* xo = x1 + (size_t)b*DCC*HWS + sp4;
    #pragma unroll
    for (int o=0;o<DCC;++o){
        ushort4v ov;
        #pragma unroll
        for (int i=0;i<4;++i) ov[i] = f2u(acc[o][i]);
        *reinterpret_cast<ushort4v*>(xo + (size_t)o*HWS) = ov;
    }
}

// ---------------------------------------------------------------- midA: lin1(h1)+gelu+dwconv+gelu + lazy-h2+gelu + gate -> g
// g is gathered in h1b (in-place over u, swizzled) then written COALESCED
// (R8 post-mortem: 128 scalar 2-B g-stores/thread pinned the kernel at ~950 GB/s).
__global__ __launch_bounds__(512) void k_midA(
    const bf16* __restrict__ x1, const bf16* __restrict__ v,
    const float* __restrict__ l1w, const float* __restrict__ l1b,
    const float* __restrict__ dww, const float* __restrict__ dwb,
    bf16* __restrict__ gout)
{
    __shared__ __align__(16) unsigned short xs[768*64];    // [px][ch] swizzled, 98304 B
    __shared__ __align__(16) unsigned short h1b[32*778];   // [cj][778] (lidx-swizzled rows), 49792 B
    const int t = threadIdx.x;
    const int lane = t & 63;
    const int w = t >> 6;
    const int col = lane & 15;
    const int g = lane >> 4;
    const int blk = blockIdx.x;
    const int b = blk >> 5;
    const int y0 = (blk & 31) << 2;

    // ---- stage x-cat: 64 ch x 6 rows(y0-1..y0+4) x 128 px, transposed+swizzled
    {
        const int ch = t & 63;
        const int wg = t >> 6;
        const bf16* src = (ch < DCC) ? x1 + ((size_t)b*DCC + ch)*HWS
                                     : v  + ((size_t)b*CC  + ch)*HWS;
        #pragma unroll
        for (int i=0;i<12;++i){
            int pxg = wg*12 + i;          // 0..95
            int bufpx = pxg << 3;
            int rr = bufpx >> 7;
            int xcol = bufpx & 127;
            int gy = y0 - 1 + rr;
            ushort8 val;
            #pragma unroll
            for (int j=0;j<8;++j) val[j] = 0;
            if (gy >= 0 && gy < HH)
                val = *reinterpret_cast<const ushort8*>(src + (size_t)gy*WW + xcol);
            #pragma unroll
            for (int j=0;j<8;++j){
                int px = bufpx + j;
                *(unsigned short*)((char*)xs + px*128 + ((ch*2) ^ ((px&7)<<4))) = val[j];
            }
        }
    }
    __syncthreads();

    const int cjdw = t & 31;          // dw: channel within chunk
    const int pxg  = (t>>5) & 15;     // dw: 8-px group

    #pragma unroll 1
    for (int cc=0; cc<4; ++cc){
        // ---- pass A fragments (h1 weights)
        bf16x8 A1h[2][2];
        #pragma unroll
        for (int t2=0;t2<2;++t2)
          #pragma unroll
          for (int kh=0;kh<2;++kh){
            bf16x8 fa;
            #pragma unroll
            for (int j=0;j<8;++j){
                int cin = kh*32 + g*8 + j;
                fa[j] = (short)f2u(l1w[cin*256 + cc*32 + t2*16 + col]);
            }
            A1h[t2][kh]=fa;
          }
        // ---- pass A: h1 chunk (32 ch) on 6 rows -> h1b (lidx rows)
        #pragma unroll
        for (int q=0;q<6;++q){
            int idx = w*6 + q;
            int rr = idx >> 3, pt = idx & 7;
            int px = rr*128 + pt*16 + col;
            int sl = lidx(rr, pt*16 + col);
            bf16x8 B0 = *(const bf16x8*)((char*)xs + px*128 + ((g*16) ^ ((px&7)<<4)));
            bf16x8 B1 = *(const bf16x8*)((char*)xs + px*128 + ((64 + g*16) ^ ((px&7)<<4)));
            f32x4 D0 = *(const f32x4*)(l1b + cc*32 + g*4);
            f32x4 D1 = *(const f32x4*)(l1b + cc*32 + 16 + g*4);
            D0 = __builtin_amdgcn_mfma_f32_16x16x32_bf16(A1h[0][0], B0, D0, 0,0,0);
            D0 = __builtin_amdgcn_mfma_f32_16x16x32_bf16(A1h[0][1], B1, D0, 0,0,0);
            D1 = __builtin_amdgcn_mfma_f32_16x16x32_bf16(A1h[1][0], B0, D1, 0,0,0);
            D1 = __builtin_amdgcn_mfma_f32_16x16x32_bf16(A1h[1][1], B1, D1, 0,0,0);
            #pragma unroll
            for (int rr2=0;rr2<4;++rr2){
                h1b[(g*4+rr2)*778 + sl]      = f2u(fgelu(D0[rr2]));
                h1b[(16+g*4+rr2)*778 + sl]   = f2u(fgelu(D1[rr2]));
            }
        }
        __syncthreads();
        // ---- dw conv (+bias+gelu) -> uv regs
        int chdw = cc*32 + cjdw;
        float w9[9];
        #pragma unroll
        for (int i=0;i<9;++i) w9[i] = dww[chdw*9+i];
        float bj = dwb[chdw];
        ushort8 uv[4];
        #pragma unroll
        for (int k=0;k<4;++k){
            float acc[8];
            #pragma unroll
            for (int i=0;i<8;++i) acc[i]=0.f;
            #pragma unroll
            for (int ky=0;ky<3;++ky){
                int gy = y0 + k + ky - 1;
                if (gy >= 0 && gy < HH){
                    const unsigned short* rowp = h1b + cjdw*778;
                    const unsigned short* rp = rowp + lidx(k+ky, pxg*8);
                    ushort8 mv = *(const ushort8*)rp;
                    float m[8];
                    #pragma unroll
                    for (int i=0;i<8;++i) m[i]=u2f(mv[i]);
                    float lf = (pxg>0)  ? u2f(rowp[lidx(k+ky, pxg*8-1)]) : 0.f;
                    float rt = (pxg<15) ? u2f(rowp[lidx(k+ky, pxg*8+8)]) : 0.f;
                    float w0=w9[ky*3], w1=w9[ky*3+1], wv2=w9[ky*3+2];
                    #pragma unroll
                    for (int i=0;i<8;++i){
                        float l  = i ? m[i-1] : lf;
                        float rr_ = (i==7) ? rt : m[i+1];
                        acc[i] = fmaf(w0,l, fmaf(w1,m[i], fmaf(wv2,rr_,acc[i])));
                    }
                }
            }
            ushort8 o;
            #pragma unroll
            for (int i=0;i<8;++i) o[i] = f2u(fgelu(acc[i]+bj));
            uv[k]=o;
        }
        __syncthreads();
        #pragma unroll
        for (int k=0;k<4;++k)
            *(ushort8*)(h1b + cjdw*778 + lidx(k+1, pxg*8)) = uv[k];
        __syncthreads();
        // ---- lazy h2 (4 MFMA per tile) + gate: g overwrites u IN PLACE (same slot,
        //      same thread -> race-free)
        bf16x8 A1g[2][2];
        #pragma unroll
        for (int t2=0;t2<2;++t2)
          #pragma unroll
          for (int kh=0;kh<2;++kh){
            bf16x8 fb;
            #pragma unroll
            for (int j=0;j<8;++j){
                int cin = kh*32 + g*8 + j;
                fb[j] = (short)f2u(l1w[cin*256 + 128 + cc*32 + t2*16 + col]);
            }
            A1g[t2][kh]=fb;
          }
        #pragma unroll
        for (int q=0;q<4;++q){
            int idx = w*4 + q;            // 0..31 = 4 rows x 8 pt
            int row = idx >> 3, pt = idx & 7;
            int px = (row+1)*128 + pt*16 + col;
            int sl = lidx(row+1, pt*16 + col);
            bf16x8 B0 = *(const bf16x8*)((char*)xs + px*128 + ((g*16) ^ ((px&7)<<4)));
            bf16x8 B1 = *(const bf16x8*)((char*)xs + px*128 + ((64 + g*16) ^ ((px&7)<<4)));
            f32x4 D0 = *(const f32x4*)(l1b + 128 + cc*32 + g*4);
            f32x4 D1 = *(const f32x4*)(l1b + 128 + cc*32 + 16 + g*4);
            D0 = __builtin_amdgcn_mfma_f32_16x16x32_bf16(A1g[0][0], B0, D0, 0,0,0);
            D0 = __builtin_amdgcn_mfma_f32_16x16x32_bf16(A1g[0][1], B1, D0, 0,0,0);
            D1 = __builtin_amdgcn_mfma_f32_16x16x32_bf16(A1g[1][0], B0, D1, 0,0,0);
            D1 = __builtin_amdgcn_mfma_f32_16x16x32_bf16(A1g[1][1], B1, D1, 0,0,0);
            #pragma unroll
            for (int rr2=0;rr2<4;++rr2){
                int cj0 = g*4 + rr2, cj1 = 16 + g*4 + rr2;
                float u0 = u2f(h1b[cj0*778 + sl]);
                float u1 = u2f(h1b[cj1*778 + sl]);
                h1b[cj0*778 + sl] = f2u(u0 * fgelu(D0[rr2]));
                h1b[cj1*778 + sl] = f2u(u1 * fgelu(D1[rr2]));
            }
        }
        __syncthreads();
        // ---- coalesced g write-back: 32 ch x 4 rows x 128 px
        {
            int ch  = t >> 4;             // 0..31
            int sub = t & 15;             // 4 rows x 4 col-blocks
            int row = sub >> 2;
            int xcol = (sub & 3) << 5;    // 32-px block
            const unsigned short* src = h1b + ch*778;
            bf16* dst = gout + ((size_t)(b*HIDN + cc*32 + ch))*HWS
                             + (size_t)(y0+row)*WW + xcol;
            #pragma unroll
            for (int i=0;i<4;++i){
                int base = lidx(row+1, xcol + i*8);
                ushort8 o;
                #pragma unroll
                for (int j=0;j<4;++j){
                    unsigned vv = *reinterpret_cast<const unsigned*>(src + base + j*2);
                    o[j*2]   = (unsigned short)(vv & 0xffff);
                    o[j*2+1] = (unsigned short)(vv >> 16);
                }
                *reinterpret_cast<ushort8*>(dst + i*8) = o;
            }
        }
        __syncthreads();
    }
}

// ---------------------------------------------------------------- midB: lin2 (128->64) + bias + residual
__global__ __launch_bounds__(512) void k_midB(
    const bf16* __restrict__ gin,
    const float* __restrict__ w2, const float* __restrict__ l2b,
    const bf16* __restrict__ v,
    bf16* __restrict__ xout,
    const float* __restrict__ xinit,   // non-null on last layer
    bf16* __restrict__ xsum)
{
    __shared__ __align__(16) unsigned short gs[HIDN*514];  // 131584 B
    const int t = threadIdx.x;
    const int lane = t & 63;
    const int w = t >> 6;
    const int col = lane & 15;
    const int g = lane >> 4;
    const int blk = blockIdx.x;
    const int b = blk >> 5;
    const int sp0 = (blk & 31) << 9;

    // ---- stage g: 128 ch x 512 px, coalesced
    {
        const int ch = t >> 2;
        const int part = t & 3;
        const bf16* gb = gin + ((size_t)(b*HIDN + ch))*HWS + sp0 + part*128;
        #pragma unroll
        for (int i=0;i<16;++i){
            ushort8 u8 = *reinterpret_cast<const ushort8*>(gb + i*8);
            *reinterpret_cast<ushort8*>(gs + ch*514 + part*128 + i*8) = u8;
        }
    }
    __syncthreads();

    bf16x8 A[4][4];
    #pragma unroll
    for (int ot=0;ot<4;++ot)
        #pragma unroll
        for (int kh=0;kh<4;++kh){
            bf16x8 f;
            #pragma unroll
            for (int j=0;j<8;++j){
                int k = kh*32 + g*8 + j;
                f[j] = (short)f2u(w2[k*64 + ot*16 + col]);
            }
            A[ot][kh] = f;
        }

    #pragma unroll 1
    for (int q=0;q<4;++q){
        int ptg = w*4 + q;               // 0..31
        int px = ptg*16 + col;
        bf16x8 Bg[4];
        #pragma unroll
        for (int kh=0;kh<4;++kh)
            #pragma unroll
            for (int j=0;j<8;++j)
                Bg[kh][j] = (short)gs[(kh*32 + g*8 + j)*514 + px];
        f32x4 D[4];
        #pragma unroll
        for (int ot=0;ot<4;++ot)
            D[ot] = *(const f32x4*)(l2b + ot*16 + g*4);
        #pragma unroll
        for (int kh=0;kh<4;++kh)
            #pragma unroll
            for (int ot=0;ot<4;++ot)
                D[ot] = __builtin_amdgcn_mfma_f32_16x16x32_bf16(A[ot][kh], Bg[kh], D[ot], 0,0,0);
        #pragma unroll
        for (int ot=0;ot<4;++ot)
            #pragma unroll
            for (int rr2=0;rr2<4;++rr2){
                int ch = ot*16 + g*4 + rr2;
                size_t off = ((size_t)(b*CC + ch))*HWS + sp0 + px;
                float rv = D[ot][rr2] + b2f(v[off]);
                *reinterpret_cast<unsigned short*>(xout + off) = f2u(rv);
                if (xinit){
                    float s = rv + xinit[off];
                    *reinterpret_cast<unsigned short*>(xsum + off) = f2u(s);
                }
            }
    }
}

// ---------------------------------------------------------------- final conv (64->1, 3x3), 4 px/thread
__global__ __launch_bounds__(256) void k_final(
    const bf16* __restrict__ s, const float* __restrict__ w,
    const float* __restrict__ bias, float* __restrict__ out)
{
    int gid = blockIdx.x*256 + threadIdx.x;
    int b = gid >> 12;
    int sp4 = (gid & 4095) << 2;
    int y = sp4 >> 7, x0 = sp4 & 127;
    const bf16* sb = s + (size_t)b*CC*HWS;
    float acc[4];
    #pragma unroll
    for (int i=0;i<4;++i) acc[i] = bias[0];

    #pragma unroll 1
    for (int c=0;c<CC;++c){
        const bf16* ip = sb + (size_t)c*HWS;
        const float* wp = w + (size_t)c*9;
        #pragma unroll
        for (int ky=0;ky<3;++ky){
            int yy = y + ky - 1;
            float xv[6];
            if (yy >= 0 && yy < HH){
                const bf16* rp = ip + yy*WW + x0;
                ushort4v mv = *reinterpret_cast<const ushort4v*>(rp);
                xv[1]=u2f(mv[0]); xv[2]=u2f(mv[1]); xv[3]=u2f(mv[2]); xv[4]=u2f(mv[3]);
                xv[0] = (x0>0)    ? b2f(rp[-1]) : 0.f;
                xv[5] = (x0+4<WW) ? b2f(rp[4])  : 0.f;
            } else {
                #pragma unroll
                for (int i=0;i<6;++i) xv[i] = 0.f;
            }
            float w0 = wp[ky*3+0], w1 = wp[ky*3+1], w2 = wp[ky*3+2];
            #pragma unroll
            for (int i=0;i<4;++i)
                acc[i] = fmaf(w0, xv[i],
                         fmaf(w1, xv[i+1],
                         fmaf(w2, xv[i+2], acc[i])));
        }
    }
    float4v ov; ov.x=acc[0]; ov.y=acc[1]; ov.z=acc[2]; ov.w=acc[3];
    *reinterpret_cast<float4v*>(out + (size_t)gid*4) = ov;
}

// ---------------------------------------------------------------- launch
extern "C" void kernel_launch(void* const* d_in, const int* in_sizes, int n_in,
                              void* d_out, int out_size, void* d_ws, size_t ws_size,
                              hipStream_t stream)
{
    const float* x    = (const float*)d_in[0];
    const float* wz1  = (const float*)d_in[1];
    const float* bz1  = (const float*)d_in[2];
    const float* wz2  = (const float*)d_in[3];
    const float* bz2  = (const float*)d_in[4];
    const float* wf1  = (const float*)d_in[5];
    const float* bf1  = (const float*)d_in[6];
    const float* wf2  = (const float*)d_in[7];
    const float* bf2  = (const float*)d_in[8];
    const float* pw   = (const float*)d_in[9];
    const float* l1w  = (const float*)d_in[10];
    const float* l1b  = (const float*)d_in[11];
    const float* dww  = (const float*)d_in[12];
    const float* dwb  = (const float*)d_in[13];
    const float* l2w  = (const float*)d_in[14];
    const float* l2b  = (const float*)d_in[15];
    const float* ow   = (const float*)d_in[16];
    const float* obb  = (const float*)d_in[17];

    char* ws = (char*)d_ws;
    bf16* xc    = (bf16*)(ws);                    // 33,554,432 B
    bf16* v     = (bf16*)(ws + 33554432);         // 33,554,432 B
    bf16* x1    = (bf16*)(ws + 67108864);         //  8,388,608 B
    bf16* xsumb = (bf16*)(ws + 75497472);         // 33,554,432 B
    bf16* gbuf  = (bf16*)(ws + 109051904);        // 67,108,864 B (total ~176 MB)

    for (int l=0;l<3;++l){
        if (l == 0)
            k_gate<1><<<512, 256, 0, stream>>>(x, nullptr,
                wz1 + l*CC*CC, bz1 + l*CC, wz2 + l*CC*CC, bz2 + l*CC,
                wf1 + l*CC*CC, bf1 + l*CC, wf2 + l*CC*CC, bf2 + l*CC, v);
        else
            k_gate<0><<<512, 256, 0, stream>>>(nullptr, xc,
                wz1 + l*CC*CC, bz1 + l*CC, wz2 + l*CC*CC, bz2 + l*CC,
                wf1 + l*CC*CC, bf1 + l*CC, wf2 + l*CC*CC, bf2 + l*CC, v);
        k_pconv<<<NPIX/(256*4), 256, 0, stream>>>(v, pw + l*DCC*DCC*9, x1);
        k_midA <<<512, 512, 0, stream>>>(x1, v,
                l1w + l*CC*256, l1b + l*256,
                dww + l*HIDN*9, dwb + l*HIDN, gbuf);
        k_midB <<<512, 512, 0, stream>>>(gbuf,
                l2w + l*HIDN*CC, l2b + l*CC, v, xc,
                (l==2) ? x : nullptr, xsumb);
    }
    k_final<<<NPIX/(256*4), 256, 0, stream>>>(xsumb, ow, obb, (float*)d_out);
}

// Round 10
// 916.577 us; speedup vs baseline: 1.1343x; 1.1343x over previous
//
#include <hip/hip_runtime.h>
#include <hip/hip_bf16.h>

#define CC 64
#define HIDN 128
#define DCC 16
#define HH 128
#define WW 128
#define HWS (HH*WW)        // 16384
#define BB 16
#define NPIX (BB*HWS)      // 262144

typedef __hip_bfloat16 bf16;
typedef __attribute__((ext_vector_type(8))) unsigned short ushort8;
typedef __attribute__((ext_vector_type(4))) unsigned short ushort4v;
typedef __attribute__((ext_vector_type(4))) float float4v;
typedef __attribute__((ext_vector_type(8))) short bf16x8;
typedef __attribute__((ext_vector_type(4))) float f32x4;

__device__ __forceinline__ float rcp_fast(float x){ return __builtin_amdgcn_rcpf(x); }
__device__ __forceinline__ float ftanh(float x){
    float e = __expf(2.f*x);
    return 1.f - 2.f*rcp_fast(e + 1.f);
}
__device__ __forceinline__ float fsig(float x){
    return rcp_fast(1.f + __expf(-x));
}
__device__ __forceinline__ float fgelu(float x){
    return x * fsig(x*(1.5957691216f + 0.07135481283f*x*x));
}
__device__ __forceinline__ float b2f(bf16 v){ return __bfloat162float(v); }
__device__ __forceinline__ bf16  f2b(float v){ return __float2bfloat16(v); }
__device__ __forceinline__ float u2f(unsigned short u){
    unsigned v = ((unsigned)u) << 16; return __uint_as_float(v);
}
__device__ __forceinline__ unsigned short f2u(float f){
    bf16 h = __float2bfloat16(f);
    return *reinterpret_cast<unsigned short*>(&h);
}
__device__ __forceinline__ bf16x8 packf(float4v a, float4v b){
    bf16x8 r;
    r[0]=(short)f2u(a.x); r[1]=(short)f2u(a.y); r[2]=(short)f2u(a.z); r[3]=(short)f2u(a.w);
    r[4]=(short)f2u(b.x); r[5]=(short)f2u(b.y); r[6]=(short)f2u(b.z); r[7]=(short)f2u(b.w);
    return r;
}

// ---------------------------------------------------------------- gate (MFMA, LDS-staged x, zero-shuffle chain)
// F32=1: read float input directly (layer 0) — replaces k_convert.
template<int F32>
__global__ __launch_bounds__(256,2) void k_gate(
    const float* __restrict__ xf, const bf16* __restrict__ xb,
    const float* __restrict__ wz1, const float* __restrict__ bz1,
    const float* __restrict__ wz2, const float* __restrict__ bz2,
    const float* __restrict__ wf1, const float* __restrict__ bf1,
    const float* __restrict__ wf2, const float* __restrict__ bf2,
    bf16* __restrict__ vout)
{
    __shared__ __align__(16) unsigned short xs[512*64];   // [px][ch] swizzled, 64 KB
    const int t = threadIdx.x;
    const int lane = t & 63;
    const int wv = t >> 6;
    const int col = lane & 15;
    const int g = lane >> 4;
    const int blk = blockIdx.x;
    const int b = blk >> 5;
    const int sp0 = (blk & 31) << 9;

    // ---- stage x: 64 ch x 512 px, coalesced loads, transposed+swizzled store
    {
        const int ch = t & 63;
        const int wg = t >> 6;
        const size_t base = ((size_t)b*CC + ch)*HWS + sp0;
        #pragma unroll
        for (int i=0;i<16;++i){
            int bufpx = (wg*16 + i) << 3;
            ushort8 val;
            if (F32){
                float4v a = *reinterpret_cast<const float4v*>(xf + base + bufpx);
                float4v c = *reinterpret_cast<const float4v*>(xf + base + bufpx + 4);
                val[0]=f2u(a.x); val[1]=f2u(a.y); val[2]=f2u(a.z); val[3]=f2u(a.w);
                val[4]=f2u(c.x); val[5]=f2u(c.y); val[6]=f2u(c.z); val[7]=f2u(c.w);
            } else {
                val = *reinterpret_cast<const ushort8*>(xb + base + bufpx);
            }
            #pragma unroll
            for (int j=0;j<8;++j){
                int px = bufpx + j;
                *(unsigned short*)((char*)xs + px*128 + ((ch*2) ^ ((px&7)<<4))) = val[j];
            }
        }
    }

    bf16x8 Az1[4][2], Af1[4][2], Az2[4][2], Af2[4][2];
    #pragma unroll
    for (int ot=0; ot<4; ++ot){
        #pragma unroll
        for (int kh=0; kh<2; ++kh){
            const float* p;
            p = wz1 + (ot*16+col)*64 + kh*32 + g*8;
            Az1[ot][kh] = packf(*(const float4v*)p, *(const float4v*)(p+4));
            p = wf1 + (ot*16+col)*64 + kh*32 + g*8;
            Af1[ot][kh] = packf(*(const float4v*)p, *(const float4v*)(p+4));
            p = wz2 + (ot*16+col)*64 + kh*32 + g*4;
            Az2[ot][kh] = packf(*(const float4v*)p, *(const float4v*)(p+16));
            p = wf2 + (ot*16+col)*64 + kh*32 + g*4;
            Af2[ot][kh] = packf(*(const float4v*)p, *(const float4v*)(p+16));
        }
    }
    __syncthreads();

    bf16* vb = vout + (size_t)b*CC*HWS;

    for (int it = wv; it < 32; it += 4){
        const int lpx = it*16 + col;
        const int px = sp0 + lpx;
        bf16x8 Bx[2];
        Bx[0] = *(const bf16x8*)((char*)xs + lpx*128 + ((g*16) ^ ((lpx&7)<<4)));
        Bx[1] = *(const bf16x8*)((char*)xs + lpx*128 + ((64 + g*16) ^ ((lpx&7)<<4)));
        f32x4 Dz[4], Df[4];
        #pragma unroll
        for (int ot=0; ot<4; ++ot){
            Dz[ot] = *(const f32x4*)(bz1 + ot*16 + g*4);
            Df[ot] = *(const f32x4*)(bf1 + ot*16 + g*4);
        }
        #pragma unroll
        for (int kh=0; kh<2; ++kh)
            #pragma unroll
            for (int ot=0; ot<4; ++ot){
                Dz[ot] = __builtin_amdgcn_mfma_f32_16x16x32_bf16(Az1[ot][kh], Bx[kh], Dz[ot], 0,0,0);
                Df[ot] = __builtin_amdgcn_mfma_f32_16x16x32_bf16(Af1[ot][kh], Bx[kh], Df[ot], 0,0,0);
            }
        #pragma unroll
        for (int ot=0; ot<4; ++ot)
            #pragma unroll
            for (int r=0; r<4; ++r){
                Dz[ot][r] = ftanh(Dz[ot][r]);
                Df[ot][r] = ftanh(Df[ot][r]);
            }
        bf16x8 Bz[2], Bf[2];
        #pragma unroll
        for (int kh=0; kh<2; ++kh)
            #pragma unroll
            for (int j=0; j<4; ++j){
                Bz[kh][j]   = (short)f2u(Dz[2*kh][j]);
                Bz[kh][4+j] = (short)f2u(Dz[2*kh+1][j]);
                Bf[kh][j]   = (short)f2u(Df[2*kh][j]);
                Bf[kh][4+j] = (short)f2u(Df[2*kh+1][j]);
            }
        f32x4 Ez[4], Ef[4];
        #pragma unroll
        for (int ot=0; ot<4; ++ot){
            Ez[ot] = *(const f32x4*)(bz2 + ot*16 + g*4);
            Ef[ot] = *(const f32x4*)(bf2 + ot*16 + g*4);
        }
        #pragma unroll
        for (int kh=0; kh<2; ++kh)
            #pragma unroll
            for (int ot=0; ot<4; ++ot){
                Ez[ot] = __builtin_amdgcn_mfma_f32_16x16x32_bf16(Az2[ot][kh], Bz[kh], Ez[ot], 0,0,0);
                Ef[ot] = __builtin_amdgcn_mfma_f32_16x16x32_bf16(Af2[ot][kh], Bf[kh], Ef[ot], 0,0,0);
            }
        #pragma unroll
        for (int ot=0; ot<4; ++ot)
            #pragma unroll
            for (int r=0; r<4; ++r){
                float Zv = ftanh(Ez[ot][r]);
                float Fv = fsig(Ef[ot][r]);
                *reinterpret_cast<unsigned short*>(vb + (size_t)(ot*16+g*4+r)*HWS + px)
                    = f2u((1.f - Fv)*Zv);
            }
    }
}

// ---------------------------------------------------------------- pconv (16->16, 3x3), 4 px/thread
__global__ __launch_bounds__(256) void k_pconv(
    const bf16* __restrict__ v, const float* __restrict__ w, bf16* __restrict__ x1)
{
    int gid = blockIdx.x*256 + threadIdx.x;
    int b = gid >> 12;
    int sp4 = (gid & 4095) << 2;
    int y = sp4 >> 7, x0 = sp4 & 127;
    const bf16* vb = v + (size_t)b*CC*HWS;
    float acc[DCC][4];
    #pragma unroll
    for (int o=0;o<DCC;++o)
        #pragma unroll
        for (int i=0;i<4;++i) acc[o][i] = 0.f;

    #pragma unroll 1
    for (int ic=0; ic<DCC; ++ic){
        const bf16* ip = vb + (size_t)ic*HWS;
        float xv[3][6];
        #pragma unroll
        for (int ky=0;ky<3;++ky){
            int yy = y + ky - 1;
            if (yy >= 0 && yy < HH){
                const bf16* rp = ip + yy*WW + x0;
                ushort4v mv = *reinterpret_cast<const ushort4v*>(rp);
                xv[ky][1]=u2f(mv[0]); xv[ky][2]=u2f(mv[1]);
                xv[ky][3]=u2f(mv[2]); xv[ky][4]=u2f(mv[3]);
                xv[ky][0] = (x0>0)     ? b2f(rp[-1]) : 0.f;
                xv[ky][5] = (x0+4<WW)  ? b2f(rp[4])  : 0.f;
            } else {
                #pragma unroll
                for (int i=0;i<6;++i) xv[ky][i] = 0.f;
            }
        }
        #pragma unroll
        for (int o=0;o<DCC;++o){
            const float* wp = w + (size_t)(o*DCC+ic)*9;
            #pragma unroll
            for (int ky=0;ky<3;++ky){
                float w0 = wp[ky*3+0], w1 = wp[ky*3+1], w2 = wp[ky*3+2];
                #pragma unroll
                for (int i=0;i<4;++i)
                    acc[o][i] = fmaf(w0, xv[ky][i],
                                fmaf(w1, xv[ky][i+1],
                                fmaf(w2, xv[ky][i+2], acc[o][i])));
            }
        }
    }
    bf16* xo = x1 + (size_t)b*DCC*HWS + sp4;
    #pragma unroll
    for (int o=0;o<DCC;++o){
        ushort4v ov;
        #pragma unroll
        for (int i=0;i<4;++i) ov[i] = f2u(acc[o][i]);
        *reinterpret_cast<ushort4v*>(xo + (size_t)o*HWS) = ov;
    }
}

// ---------------------------------------------------------------- midA: lin1(h1)+gelu+dwconv+gelu + lazy-h2+gelu + gate -> g
// 1 OUTPUT ROW per block, 256 thr (4 waves). LDS 74 KB -> 2 blocks/CU
// (R8 post-mortem: 148 KB variant was 1 block/CU, barrier/latency-bound at
// 2 waves/SIMD with nothing co-resident to overlap its 13 barriers).
__global__ __launch_bounds__(256,2) void k_midA(
    const bf16* __restrict__ x1, const bf16* __restrict__ v,
    const float* __restrict__ l1w, const float* __restrict__ l1b,
    const float* __restrict__ dww, const float* __restrict__ dwb,
    bf16* __restrict__ gout)
{
    __shared__ __align__(16) unsigned short xs[384*64];    // [px(3rows)][ch] swizzled, 49152 B
    __shared__ __align__(16) unsigned short h1b[32*390];   // [cj][3*128+pad], 24960 B
    const int t = threadIdx.x;
    const int lane = t & 63;
    const int w = t >> 6;          // 0..3
    const int col = lane & 15;
    const int g = lane >> 4;
    const int blk = blockIdx.x;
    const int b = blk >> 7;
    const int y = blk & 127;       // output row

    // ---- stage x-cat: 64 ch x 3 rows(y-1..y+1) x 128 px, transposed+swizzled
    {
        const int ch = t & 63;
        const int wg = t >> 6;
        const bf16* src = (ch < DCC) ? x1 + ((size_t)b*DCC + ch)*HWS
                                     : v  + ((size_t)b*CC  + ch)*HWS;
        #pragma unroll
        for (int i=0;i<12;++i){
            int pxg = wg*12 + i;          // 0..47
            int bufpx = pxg << 3;
            int rr = bufpx >> 7;
            int xcol = bufpx & 127;
            int gy = y - 1 + rr;
            ushort8 val;
            #pragma unroll
            for (int j=0;j<8;++j) val[j] = 0;
            if (gy >= 0 && gy < HH)
                val = *reinterpret_cast<const ushort8*>(src + (size_t)gy*WW + xcol);
            #pragma unroll
            for (int j=0;j<8;++j){
                int px = bufpx + j;
                *(unsigned short*)((char*)xs + px*128 + ((ch*2) ^ ((px&7)<<4))) = val[j];
            }
        }
    }
    __syncthreads();

    const int cjdw = t & 31;          // dw: channel within chunk
    const int pxg  = t >> 5;          // dw: 16-px group, 0..7

    #pragma unroll 1
    for (int cc=0; cc<4; ++cc){
        // ---- pass A fragments (h1 weights)
        bf16x8 A1h[2][2];
        #pragma unroll
        for (int t2=0;t2<2;++t2)
          #pragma unroll
          for (int kh=0;kh<2;++kh){
            bf16x8 fa;
            #pragma unroll
            for (int j=0;j<8;++j){
                int cin = kh*32 + g*8 + j;
                fa[j] = (short)f2u(l1w[cin*256 + cc*32 + t2*16 + col]);
            }
            A1h[t2][kh]=fa;
          }
        // ---- pass A: h1 chunk (32 ch) on 3 rows -> h1b
        #pragma unroll
        for (int q=0;q<6;++q){
            int idx = w*6 + q;            // 0..23
            int rr = idx >> 3, pt = idx & 7;
            int px = rr*128 + pt*16 + col;
            bf16x8 B0 = *(const bf16x8*)((char*)xs + px*128 + ((g*16) ^ ((px&7)<<4)));
            bf16x8 B1 = *(const bf16x8*)((char*)xs + px*128 + ((64 + g*16) ^ ((px&7)<<4)));
            f32x4 D0 = *(const f32x4*)(l1b + cc*32 + g*4);
            f32x4 D1 = *(const f32x4*)(l1b + cc*32 + 16 + g*4);
            D0 = __builtin_amdgcn_mfma_f32_16x16x32_bf16(A1h[0][0], B0, D0, 0,0,0);
            D0 = __builtin_amdgcn_mfma_f32_16x16x32_bf16(A1h[0][1], B1, D0, 0,0,0);
            D1 = __builtin_amdgcn_mfma_f32_16x16x32_bf16(A1h[1][0], B0, D1, 0,0,0);
            D1 = __builtin_amdgcn_mfma_f32_16x16x32_bf16(A1h[1][1], B1, D1, 0,0,0);
            #pragma unroll
            for (int rr2=0;rr2<4;++rr2){
                h1b[(g*4+rr2)*390 + px]      = f2u(fgelu(D0[rr2]));
                h1b[(16+g*4+rr2)*390 + px]   = f2u(fgelu(D1[rr2]));
            }
        }
        __syncthreads();
        // ---- dw conv (+bias+gelu), 1 ch x 16 px per thread
        int chdw = cc*32 + cjdw;
        float w9[9];
        #pragma unroll
        for (int i=0;i<9;++i) w9[i] = dww[chdw*9+i];
        float bj = dwb[chdw];
        float acc[16];
        #pragma unroll
        for (int i=0;i<16;++i) acc[i]=0.f;
        #pragma unroll
        for (int ky=0; ky<3; ++ky){
            int gy = y + ky - 1;
            if (gy < 0 || gy >= HH) continue;
            const unsigned short* rp = h1b + cjdw*390 + ky*128 + pxg*16;
            float m[16];
            {
                ushort8 a = *(const ushort8*)rp;
                ushort8 c = *(const ushort8*)(rp+8);
                #pragma unroll
                for (int i=0;i<8;++i){ m[i]=u2f(a[i]); m[8+i]=u2f(c[i]); }
            }
            float lf = (pxg>0) ? u2f(rp[-1]) : 0.f;
            float rt = (pxg<7) ? u2f(rp[16]) : 0.f;
            float w0=w9[ky*3], w1=w9[ky*3+1], wv2=w9[ky*3+2];
            #pragma unroll
            for (int i=0;i<16;++i){
                float l  = i ? m[i-1] : lf;
                float r_ = (i==15) ? rt : m[i+1];
                acc[i] = fmaf(w0,l, fmaf(w1,m[i], fmaf(wv2,r_,acc[i])));
            }
        }
        ushort8 o0, o1;
        #pragma unroll
        for (int i=0;i<8;++i){
            o0[i] = f2u(fgelu(acc[i]+bj));
            o1[i] = f2u(fgelu(acc[8+i]+bj));
        }
        __syncthreads();
        *(ushort8*)(h1b + cjdw*390 + 128 + pxg*16)     = o0;
        *(ushort8*)(h1b + cjdw*390 + 128 + pxg*16 + 8) = o1;
        __syncthreads();
        // ---- lazy h2 (4 MFMA per tile) + gate, write g to global
        bf16x8 A1g[2][2];
        #pragma unroll
        for (int t2=0;t2<2;++t2)
          #pragma unroll
          for (int kh=0;kh<2;++kh){
            bf16x8 fb;
            #pragma unroll
            for (int j=0;j<8;++j){
                int cin = kh*32 + g*8 + j;
                fb[j] = (short)f2u(l1w[cin*256 + 128 + cc*32 + t2*16 + col]);
            }
            A1g[t2][kh]=fb;
          }
        #pragma unroll
        for (int q=0;q<2;++q){
            int pt = w*2 + q;             // 0..7
            int px = 128 + pt*16 + col;   // center row of xs
            bf16x8 B0 = *(const bf16x8*)((char*)xs + px*128 + ((g*16) ^ ((px&7)<<4)));
            bf16x8 B1 = *(const bf16x8*)((char*)xs + px*128 + ((64 + g*16) ^ ((px&7)<<4)));
            f32x4 D0 = *(const f32x4*)(l1b + 128 + cc*32 + g*4);
            f32x4 D1 = *(const f32x4*)(l1b + 128 + cc*32 + 16 + g*4);
            D0 = __builtin_amdgcn_mfma_f32_16x16x32_bf16(A1g[0][0], B0, D0, 0,0,0);
            D0 = __builtin_amdgcn_mfma_f32_16x16x32_bf16(A1g[0][1], B1, D0, 0,0,0);
            D1 = __builtin_amdgcn_mfma_f32_16x16x32_bf16(A1g[1][0], B0, D1, 0,0,0);
            D1 = __builtin_amdgcn_mfma_f32_16x16x32_bf16(A1g[1][1], B1, D1, 0,0,0);
            size_t pix = (size_t)y*WW + pt*16 + col;
            #pragma unroll
            for (int rr2=0;rr2<4;++rr2){
                int cj0 = g*4 + rr2, cj1 = 16 + g*4 + rr2;
                float u0 = u2f(h1b[cj0*390 + px]);
                float u1 = u2f(h1b[cj1*390 + px]);
                *reinterpret_cast<unsigned short*>(gout + ((size_t)(b*HIDN + cc*32 + cj0))*HWS + pix)
                    = f2u(u0 * fgelu(D0[rr2]));
                *reinterpret_cast<unsigned short*>(gout + ((size_t)(b*HIDN + cc*32 + cj1))*HWS + pix)
                    = f2u(u1 * fgelu(D1[rr2]));
            }
        }
        __syncthreads();
    }
}

// ---------------------------------------------------------------- midB: lin2 (128->64) + bias + residual
// 256-px tiles -> 66 KB LDS -> 2 blocks/CU (R8's 512-px/131 KB was 1 block/CU).
__global__ __launch_bounds__(512,2) void k_midB(
    const bf16* __restrict__ gin,
    const float* __restrict__ w2, const float* __restrict__ l2b,
    const bf16* __restrict__ v,
    bf16* __restrict__ xout,
    const float* __restrict__ xinit,   // non-null on last layer
    bf16* __restrict__ xsum)
{
    __shared__ __align__(16) unsigned short gs[HIDN*258];  // 66048 B
    const int t = threadIdx.x;
    const int lane = t & 63;
    const int w = t >> 6;
    const int col = lane & 15;
    const int g = lane >> 4;
    const int blk = blockIdx.x;
    const int b = blk >> 6;
    const int sp0 = (blk & 63) << 8;

    // ---- stage g: 128 ch x 256 px, coalesced
    {
        const int ch = t >> 2;
        const int part = t & 3;
        const bf16* gb = gin + ((size_t)(b*HIDN + ch))*HWS + sp0 + part*64;
        #pragma unroll
        for (int i=0;i<8;++i){
            ushort8 u8 = *reinterpret_cast<const ushort8*>(gb + i*8);
            *reinterpret_cast<ushort8*>(gs + ch*258 + part*64 + i*8) = u8;
        }
    }
    __syncthreads();

    bf16x8 A[4][4];
    #pragma unroll
    for (int ot=0;ot<4;++ot)
        #pragma unroll
        for (int kh=0;kh<4;++kh){
            bf16x8 f;
            #pragma unroll
            for (int j=0;j<8;++j){
                int k = kh*32 + g*8 + j;
                f[j] = (short)f2u(w2[k*64 + ot*16 + col]);
            }
            A[ot][kh] = f;
        }

    #pragma unroll 1
    for (int q=0;q<2;++q){
        int ptg = w*2 + q;               // 0..15
        int px = ptg*16 + col;
        bf16x8 Bg[4];
        #pragma unroll
        for (int kh=0;kh<4;++kh)
            #pragma unroll
            for (int j=0;j<8;++j)
                Bg[kh][j] = (short)gs[(kh*32 + g*8 + j)*258 + px];
        f32x4 D[4];
        #pragma unroll
        for (int ot=0;ot<4;++ot)
            D[ot] = *(const f32x4*)(l2b + ot*16 + g*4);
        #pragma unroll
        for (int kh=0;kh<4;++kh)
            #pragma unroll
            for (int ot=0;ot<4;++ot)
                D[ot] = __builtin_amdgcn_mfma_f32_16x16x32_bf16(A[ot][kh], Bg[kh], D[ot], 0,0,0);
        #pragma unroll
        for (int ot=0;ot<4;++ot)
            #pragma unroll
            for (int rr2=0;rr2<4;++rr2){
                int ch = ot*16 + g*4 + rr2;
                size_t off = ((size_t)(b*CC + ch))*HWS + sp0 + px;
                float rv = D[ot][rr2] + b2f(v[off]);
                *reinterpret_cast<unsigned short*>(xout + off) = f2u(rv);
                if (xinit){
                    float s = rv + xinit[off];
                    *reinterpret_cast<unsigned short*>(xsum + off) = f2u(s);
                }
            }
    }
}

// ---------------------------------------------------------------- final conv (64->1, 3x3), 4 px/thread
__global__ __launch_bounds__(256) void k_final(
    const bf16* __restrict__ s, const float* __restrict__ w,
    const float* __restrict__ bias, float* __restrict__ out)
{
    int gid = blockIdx.x*256 + threadIdx.x;
    int b = gid >> 12;
    int sp4 = (gid & 4095) << 2;
    int y = sp4 >> 7, x0 = sp4 & 127;
    const bf16* sb = s + (size_t)b*CC*HWS;
    float acc[4];
    #pragma unroll
    for (int i=0;i<4;++i) acc[i] = bias[0];

    #pragma unroll 1
    for (int c=0;c<CC;++c){
        const bf16* ip = sb + (size_t)c*HWS;
        const float* wp = w + (size_t)c*9;
        #pragma unroll
        for (int ky=0;ky<3;++ky){
            int yy = y + ky - 1;
            float xv[6];
            if (yy >= 0 && yy < HH){
                const bf16* rp = ip + yy*WW + x0;
                ushort4v mv = *reinterpret_cast<const ushort4v*>(rp);
                xv[1]=u2f(mv[0]); xv[2]=u2f(mv[1]); xv[3]=u2f(mv[2]); xv[4]=u2f(mv[3]);
                xv[0] = (x0>0)    ? b2f(rp[-1]) : 0.f;
                xv[5] = (x0+4<WW) ? b2f(rp[4])  : 0.f;
            } else {
                #pragma unroll
                for (int i=0;i<6;++i) xv[i] = 0.f;
            }
            float w0 = wp[ky*3+0], w1 = wp[ky*3+1], w2 = wp[ky*3+2];
            #pragma unroll
            for (int i=0;i<4;++i)
                acc[i] = fmaf(w0, xv[i],
                         fmaf(w1, xv[i+1],
                         fmaf(w2, xv[i+2], acc[i])));
        }
    }
    float4v ov; ov.x=acc[0]; ov.y=acc[1]; ov.z=acc[2]; ov.w=acc[3];
    *reinterpret_cast<float4v*>(out + (size_t)gid*4) = ov;
}

// ---------------------------------------------------------------- launch
extern "C" void kernel_launch(void* const* d_in, const int* in_sizes, int n_in,
                              void* d_out, int out_size, void* d_ws, size_t ws_size,
                              hipStream_t stream)
{
    const float* x    = (const float*)d_in[0];
    const float* wz1  = (const float*)d_in[1];
    const float* bz1  = (const float*)d_in[2];
    const float* wz2  = (const float*)d_in[3];
    const float* bz2  = (const float*)d_in[4];
    const float* wf1  = (const float*)d_in[5];
    const float* bf1  = (const float*)d_in[6];
    const float* wf2  = (const float*)d_in[7];
    const float* bf2  = (const float*)d_in[8];
    const float* pw   = (const float*)d_in[9];
    const float* l1w  = (const float*)d_in[10];
    const float* l1b  = (const float*)d_in[11];
    const float* dww  = (const float*)d_in[12];
    const float* dwb  = (const float*)d_in[13];
    const float* l2w  = (const float*)d_in[14];
    const float* l2b  = (const float*)d_in[15];
    const float* ow   = (const float*)d_in[16];
    const float* obb  = (const float*)d_in[17];

    char* ws = (char*)d_ws;
    bf16* xc    = (bf16*)(ws);                    // 33,554,432 B
    bf16* v     = (bf16*)(ws + 33554432);         // 33,554,432 B
    bf16* x1    = (bf16*)(ws + 67108864);         //  8,388,608 B
    bf16* xsumb = (bf16*)(ws + 75497472);         // 33,554,432 B
    bf16* gbuf  = (bf16*)(ws + 109051904);        // 67,108,864 B (total ~176 MB)

    for (int l=0;l<3;++l){
        if (l == 0)
            k_gate<1><<<512, 256, 0, stream>>>(x, nullptr,
                wz1 + l*CC*CC, bz1 + l*CC, wz2 + l*CC*CC, bz2 + l*CC,
                wf1 + l*CC*CC, bf1 + l*CC, wf2 + l*CC*CC, bf2 + l*CC, v);
        else
            k_gate<0><<<512, 256, 0, stream>>>(nullptr, xc,
                wz1 + l*CC*CC, bz1 + l*CC, wz2 + l*CC*CC, bz2 + l*CC,
                wf1 + l*CC*CC, bf1 + l*CC, wf2 + l*CC*CC, bf2 + l*CC, v);
        k_pconv<<<NPIX/(256*4), 256, 0, stream>>>(v, pw + l*DCC*DCC*9, x1);
        k_midA <<<BB*HH, 256, 0, stream>>>(x1, v,
                l1w + l*CC*256, l1b + l*256,
                dww + l*HIDN*9, dwb + l*HIDN, gbuf);
        k_midB <<<BB*(HWS/256), 512, 0, stream>>>(gbuf,
                l2w + l*HIDN*CC, l2b + l*CC, v, xc,
                (l==2) ? x : nullptr, xsumb);
    }
    k_final<<<NPIX/(256*4), 256, 0, stream>>>(xsumb, ow, obb, (float*)d_out);
}

// Round 11
// 860.898 us; speedup vs baseline: 1.2077x; 1.0647x over previous
//
#include <hip/hip_runtime.h>
#include <hip/hip_bf16.h>

#define CC 64
#define HIDN 128
#define DCC 16
#define HH 128
#define WW 128
#define HWS (HH*WW)        // 16384
#define BB 16
#define NPIX (BB*HWS)      // 262144

typedef __hip_bfloat16 bf16;
typedef __attribute__((ext_vector_type(8))) unsigned short ushort8;
typedef __attribute__((ext_vector_type(4))) unsigned short ushort4v;
typedef __attribute__((ext_vector_type(4))) float float4v;
typedef __attribute__((ext_vector_type(8))) short bf16x8;
typedef __attribute__((ext_vector_type(4))) float f32x4;

__device__ __forceinline__ float rcp_fast(float x){ return __builtin_amdgcn_rcpf(x); }
__device__ __forceinline__ float ftanh(float x){
    float e = __expf(2.f*x);
    return 1.f - 2.f*rcp_fast(e + 1.f);
}
__device__ __forceinline__ float fsig(float x){
    return rcp_fast(1.f + __expf(-x));
}
__device__ __forceinline__ float fgelu(float x){
    return x * fsig(x*(1.5957691216f + 0.07135481283f*x*x));
}
__device__ __forceinline__ float b2f(bf16 v){ return __bfloat162float(v); }
__device__ __forceinline__ float u2f(unsigned short u){
    unsigned v = ((unsigned)u) << 16; return __uint_as_float(v);
}
__device__ __forceinline__ unsigned short f2u(float f){
    bf16 h = __float2bfloat16(f);
    return *reinterpret_cast<unsigned short*>(&h);
}
__device__ __forceinline__ bf16x8 packf(float4v a, float4v b){
    bf16x8 r;
    r[0]=(short)f2u(a.x); r[1]=(short)f2u(a.y); r[2]=(short)f2u(a.z); r[3]=(short)f2u(a.w);
    r[4]=(short)f2u(b.x); r[5]=(short)f2u(b.y); r[6]=(short)f2u(b.z); r[7]=(short)f2u(b.w);
    return r;
}

// ---------------------------------------------------------------- gate (MFMA, LDS-staged x, zero-shuffle chain)
template<int F32>
__global__ __launch_bounds__(256,2) void k_gate(
    const float* __restrict__ xf, const bf16* __restrict__ xb,
    const float* __restrict__ wz1, const float* __restrict__ bz1,
    const float* __restrict__ wz2, const float* __restrict__ bz2,
    const float* __restrict__ wf1, const float* __restrict__ bf1,
    const float* __restrict__ wf2, const float* __restrict__ bf2,
    bf16* __restrict__ vout)
{
    __shared__ __align__(16) unsigned short xs[512*64];   // 64 KB
    const int t = threadIdx.x;
    const int lane = t & 63;
    const int wv = t >> 6;
    const int col = lane & 15;
    const int g = lane >> 4;
    const int blk = blockIdx.x;
    const int b = blk >> 5;
    const int sp0 = (blk & 31) << 9;

    {
        const int ch = t & 63;
        const int wg = t >> 6;
        const size_t base = ((size_t)b*CC + ch)*HWS + sp0;
        #pragma unroll
        for (int i=0;i<16;++i){
            int bufpx = (wg*16 + i) << 3;
            ushort8 val;
            if (F32){
                float4v a = *reinterpret_cast<const float4v*>(xf + base + bufpx);
                float4v c = *reinterpret_cast<const float4v*>(xf + base + bufpx + 4);
                val[0]=f2u(a.x); val[1]=f2u(a.y); val[2]=f2u(a.z); val[3]=f2u(a.w);
                val[4]=f2u(c.x); val[5]=f2u(c.y); val[6]=f2u(c.z); val[7]=f2u(c.w);
            } else {
                val = *reinterpret_cast<const ushort8*>(xb + base + bufpx);
            }
            #pragma unroll
            for (int j=0;j<8;++j){
                int px = bufpx + j;
                *(unsigned short*)((char*)xs + px*128 + ((ch*2) ^ ((px&7)<<4))) = val[j];
            }
        }
    }

    bf16x8 Az1[4][2], Af1[4][2], Az2[4][2], Af2[4][2];
    #pragma unroll
    for (int ot=0; ot<4; ++ot){
        #pragma unroll
        for (int kh=0; kh<2; ++kh){
            const float* p;
            p = wz1 + (ot*16+col)*64 + kh*32 + g*8;
            Az1[ot][kh] = packf(*(const float4v*)p, *(const float4v*)(p+4));
            p = wf1 + (ot*16+col)*64 + kh*32 + g*8;
            Af1[ot][kh] = packf(*(const float4v*)p, *(const float4v*)(p+4));
            p = wz2 + (ot*16+col)*64 + kh*32 + g*4;
            Az2[ot][kh] = packf(*(const float4v*)p, *(const float4v*)(p+16));
            p = wf2 + (ot*16+col)*64 + kh*32 + g*4;
            Af2[ot][kh] = packf(*(const float4v*)p, *(const float4v*)(p+16));
        }
    }
    __syncthreads();

    bf16* vb = vout + (size_t)b*CC*HWS;

    for (int it = wv; it < 32; it += 4){
        const int lpx = it*16 + col;
        const int px = sp0 + lpx;
        bf16x8 Bx[2];
        Bx[0] = *(const bf16x8*)((char*)xs + lpx*128 + ((g*16) ^ ((lpx&7)<<4)));
        Bx[1] = *(const bf16x8*)((char*)xs + lpx*128 + ((64 + g*16) ^ ((lpx&7)<<4)));
        f32x4 Dz[4], Df[4];
        #pragma unroll
        for (int ot=0; ot<4; ++ot){
            Dz[ot] = *(const f32x4*)(bz1 + ot*16 + g*4);
            Df[ot] = *(const f32x4*)(bf1 + ot*16 + g*4);
        }
        #pragma unroll
        for (int kh=0; kh<2; ++kh)
            #pragma unroll
            for (int ot=0; ot<4; ++ot){
                Dz[ot] = __builtin_amdgcn_mfma_f32_16x16x32_bf16(Az1[ot][kh], Bx[kh], Dz[ot], 0,0,0);
                Df[ot] = __builtin_amdgcn_mfma_f32_16x16x32_bf16(Af1[ot][kh], Bx[kh], Df[ot], 0,0,0);
            }
        #pragma unroll
        for (int ot=0; ot<4; ++ot)
            #pragma unroll
            for (int r=0; r<4; ++r){
                Dz[ot][r] = ftanh(Dz[ot][r]);
                Df[ot][r] = ftanh(Df[ot][r]);
            }
        bf16x8 Bz[2], Bf[2];
        #pragma unroll
        for (int kh=0; kh<2; ++kh)
            #pragma unroll
            for (int j=0; j<4; ++j){
                Bz[kh][j]   = (short)f2u(Dz[2*kh][j]);
                Bz[kh][4+j] = (short)f2u(Dz[2*kh+1][j]);
                Bf[kh][j]   = (short)f2u(Df[2*kh][j]);
                Bf[kh][4+j] = (short)f2u(Df[2*kh+1][j]);
            }
        f32x4 Ez[4], Ef[4];
        #pragma unroll
        for (int ot=0; ot<4; ++ot){
            Ez[ot] = *(const f32x4*)(bz2 + ot*16 + g*4);
            Ef[ot] = *(const f32x4*)(bf2 + ot*16 + g*4);
        }
        #pragma unroll
        for (int kh=0; kh<2; ++kh)
            #pragma unroll
            for (int ot=0; ot<4; ++ot){
                Ez[ot] = __builtin_amdgcn_mfma_f32_16x16x32_bf16(Az2[ot][kh], Bz[kh], Ez[ot], 0,0,0);
                Ef[ot] = __builtin_amdgcn_mfma_f32_16x16x32_bf16(Af2[ot][kh], Bf[kh], Ef[ot], 0,0,0);
            }
        #pragma unroll
        for (int ot=0; ot<4; ++ot)
            #pragma unroll
            for (int r=0; r<4; ++r){
                float Zv = ftanh(Ez[ot][r]);
                float Fv = fsig(Ef[ot][r]);
                *reinterpret_cast<unsigned short*>(vb + (size_t)(ot*16+g*4+r)*HWS + px)
                    = f2u((1.f - Fv)*Zv);
            }
    }
}

// ---------------------------------------------------------------- pconv (16->16, 3x3), 4 px/thread
__global__ __launch_bounds__(256) void k_pconv(
    const bf16* __restrict__ v, const float* __restrict__ w, bf16* __restrict__ x1)
{
    int gid = blockIdx.x*256 + threadIdx.x;
    int b = gid >> 12;
    int sp4 = (gid & 4095) << 2;
    int y = sp4 >> 7, x0 = sp4 & 127;
    const bf16* vb = v + (size_t)b*CC*HWS;
    float acc[DCC][4];
    #pragma unroll
    for (int o=0;o<DCC;++o)
        #pragma unroll
        for (int i=0;i<4;++i) acc[o][i] = 0.f;

    #pragma unroll 1
    for (int ic=0; ic<DCC; ++ic){
        const bf16* ip = vb + (size_t)ic*HWS;
        float xv[3][6];
        #pragma unroll
        for (int ky=0;ky<3;++ky){
            int yy = y + ky - 1;
            if (yy >= 0 && yy < HH){
                const bf16* rp = ip + yy*WW + x0;
                ushort4v mv = *reinterpret_cast<const ushort4v*>(rp);
                xv[ky][1]=u2f(mv[0]); xv[ky][2]=u2f(mv[1]);
                xv[ky][3]=u2f(mv[2]); xv[ky][4]=u2f(mv[3]);
                xv[ky][0] = (x0>0)     ? b2f(rp[-1]) : 0.f;
                xv[ky][5] = (x0+4<WW)  ? b2f(rp[4])  : 0.f;
            } else {
                #pragma unroll
                for (int i=0;i<6;++i) xv[ky][i] = 0.f;
            }
        }
        #pragma unroll
        for (int o=0;o<DCC;++o){
            const float* wp = w + (size_t)(o*DCC+ic)*9;
            #pragma unroll
            for (int ky=0;ky<3;++ky){
                float w0 = wp[ky*3+0], w1 = wp[ky*3+1], w2 = wp[ky*3+2];
                #pragma unroll
                for (int i=0;i<4;++i)
                    acc[o][i] = fmaf(w0, xv[ky][i],
                                fmaf(w1, xv[ky][i+1],
                                fmaf(w2, xv[ky][i+2], acc[o][i])));
            }
        }
    }
    bf16* xo = x1 + (size_t)b*DCC*HWS + sp4;
    #pragma unroll
    for (int o=0;o<DCC;++o){
        ushort4v ov;
        #pragma unroll
        for (int i=0;i<4;++i) ov[i] = f2u(acc[o][i]);
        *reinterpret_cast<ushort4v*>(xo + (size_t)o*HWS) = ov;
    }
}

// ---------------------------------------------------------------- lin1h: h1 = gelu(lin1_h(xcat)), computed ONCE per px.
// 256-px blocks, 1 barrier; wave-private LDS transpose -> fully coalesced h1 stores.
__global__ __launch_bounds__(256) void k_lin1h(
    const bf16* __restrict__ x1, const bf16* __restrict__ v,
    const float* __restrict__ l1w, const float* __restrict__ l1b,
    bf16* __restrict__ h1out)
{
    __shared__ __align__(16) unsigned short xs[256*64];   // 32 KB
    __shared__ __align__(16) unsigned short tr[4][32*66]; // 16.5 KB, wave-private
    const int t = threadIdx.x;
    const int lane = t & 63;
    const int wv = t >> 6;
    const int col = lane & 15;
    const int g = lane >> 4;
    const int blk = blockIdx.x;         // 1024 blocks
    const int b = blk >> 6;
    const int sp0 = (blk & 63) << 8;

    {   // stage x-cat 64ch x 256px transposed+swizzled
        const int ch = t & 63;
        const int wg = t >> 6;
        const bf16* src = (ch < DCC) ? x1 + ((size_t)b*DCC + ch)*HWS
                                     : v  + ((size_t)b*CC  + ch)*HWS;
        #pragma unroll
        for (int i=0;i<8;++i){
            int bufpx = (wg*8 + i) << 3;
            ushort8 val = *reinterpret_cast<const ushort8*>(src + sp0 + bufpx);
            #pragma unroll
            for (int j=0;j<8;++j){
                int px = bufpx + j;
                *(unsigned short*)((char*)xs + px*128 + ((ch*2) ^ ((px&7)<<4))) = val[j];
            }
        }
    }
    __syncthreads();

    unsigned short* trw = &tr[wv][0];
    const int lpx0 = wv*64;

    #pragma unroll 1
    for (int oc=0; oc<4; ++oc){
        bf16x8 A1[2][2];
        #pragma unroll
        for (int t2=0;t2<2;++t2)
            #pragma unroll
            for (int kh=0;kh<2;++kh){
                bf16x8 fa;
                #pragma unroll
                for (int j=0;j<8;++j){
                    int cin = kh*32 + g*8 + j;
                    fa[j] = (short)f2u(l1w[cin*256 + oc*32 + t2*16 + col]);
                }
                A1[t2][kh]=fa;
            }
        #pragma unroll
        for (int lt=0;lt<4;++lt){
            int px = lpx0 + lt*16 + col;
            bf16x8 B0 = *(const bf16x8*)((char*)xs + px*128 + ((g*16) ^ ((px&7)<<4)));
            bf16x8 B1 = *(const bf16x8*)((char*)xs + px*128 + ((64 + g*16) ^ ((px&7)<<4)));
            f32x4 D0 = *(const f32x4*)(l1b + oc*32 + g*4);
            f32x4 D1 = *(const f32x4*)(l1b + oc*32 + 16 + g*4);
            D0 = __builtin_amdgcn_mfma_f32_16x16x32_bf16(A1[0][0], B0, D0, 0,0,0);
            D0 = __builtin_amdgcn_mfma_f32_16x16x32_bf16(A1[0][1], B1, D0, 0,0,0);
            D1 = __builtin_amdgcn_mfma_f32_16x16x32_bf16(A1[1][0], B0, D1, 0,0,0);
            D1 = __builtin_amdgcn_mfma_f32_16x16x32_bf16(A1[1][1], B1, D1, 0,0,0);
            int lp = lt*16 + col;
            #pragma unroll
            for (int rr=0;rr<4;++rr){
                trw[(g*4+rr)*66 + lp]    = f2u(fgelu(D0[rr]));
                trw[(16+g*4+rr)*66 + lp] = f2u(fgelu(D1[rr]));
            }
        }
        // wave-private transpose read + coalesced store (no barrier needed)
        {
            int ch2 = lane >> 1;
            int half = lane & 1;
            const unsigned short* srcp = trw + ch2*66 + half*32;
            bf16* dst = h1out + ((size_t)(b*HIDN + oc*32 + ch2))*HWS + sp0 + lpx0 + half*32;
            #pragma unroll
            for (int i=0;i<4;++i){
                ushort8 u8 = *reinterpret_cast<const ushort8*>(srcp + i*8);
                *reinterpret_cast<ushort8*>(dst + i*8) = u8;
            }
        }
    }
}

// ---------------------------------------------------------------- dwA: dwconv(h1)+gelu + lazy-h2+gelu + gate + lin2 + residual
// 1 row per block, 256 thr. g lives only in LDS; lin2 accum = 32 VGPR/thread.
__global__ __launch_bounds__(256) void k_dwA(
    const bf16* __restrict__ x1, const bf16* __restrict__ v,
    const bf16* __restrict__ h1,
    const float* __restrict__ l1w, const float* __restrict__ l1b,
    const float* __restrict__ dww, const float* __restrict__ dwb,
    const float* __restrict__ w2,  const float* __restrict__ l2b,
    bf16* __restrict__ xout,
    const float* __restrict__ xinit,   // non-null on last layer
    bf16* __restrict__ xsum)
{
    __shared__ __align__(16) unsigned short xs[128*64];   // 16 KB (center row)
    __shared__ __align__(16) unsigned short ub[32*260];   // 16.6 KB (u then g per chunk)
    const int t = threadIdx.x;
    const int lane = t & 63;
    const int wv = t >> 6;
    const int col = lane & 15;
    const int g = lane >> 4;
    const int blk = blockIdx.x;          // 2048 blocks
    const int b = blk >> 7;
    const int y = blk & 127;

    {   // stage x-cat center row: 64ch x 128px
        const int ch = t & 63;
        const int wg = t >> 6;
        const bf16* src = (ch < DCC) ? x1 + ((size_t)b*DCC + ch)*HWS
                                     : v  + ((size_t)b*CC  + ch)*HWS;
        #pragma unroll
        for (int i=0;i<2;++i){
            int bufpx = (wg*2 + i) << 3;
            ushort8 val = *reinterpret_cast<const ushort8*>(src + (size_t)y*WW + bufpx);
            #pragma unroll
            for (int j=0;j<8;++j){
                int px = bufpx + j;
                *(unsigned short*)((char*)xs + px*128 + ((ch*2) ^ ((px&7)<<4))) = val[j];
            }
        }
    }
    __syncthreads();

    // lin2 accumulators: wave owns px tiles pt=wv*2, wv*2+1; 64 out-ch (4 ot)
    f32x4 Dx[2][4];
    #pragma unroll
    for (int q=0;q<2;++q)
        #pragma unroll
        for (int ot=0;ot<4;++ot)
            Dx[q][ot] = *(const f32x4*)(l2b + ot*16 + g*4);

    const int cj  = (t>>3) & 31;     // dw channel within chunk
    const int pxo = (t & 7) << 4;    // dw 16-px group

    #pragma unroll 1
    for (int cc=0; cc<4; ++cc){
        // ---- dw conv from global h1 (rows y-1..y+1) -> u in LDS
        {
            int chg = cc*32 + cj;
            const bf16* h1p = h1 + ((size_t)(b*HIDN + chg))*HWS;
            float w9[9];
            #pragma unroll
            for (int i=0;i<9;++i) w9[i] = dww[chg*9+i];
            float bj = dwb[chg];
            float acc[16];
            #pragma unroll
            for (int i=0;i<16;++i) acc[i]=0.f;
            #pragma unroll
            for (int ky=0; ky<3; ++ky){
                int gy = y + ky - 1;
                if (gy < 0 || gy >= HH) continue;
                const bf16* rp = h1p + (size_t)gy*WW + pxo;
                float m[16];
                {
                    ushort8 a = *reinterpret_cast<const ushort8*>(rp);
                    ushort8 c = *reinterpret_cast<const ushort8*>(rp+8);
                    #pragma unroll
                    for (int i=0;i<8;++i){ m[i]=u2f(a[i]); m[8+i]=u2f(c[i]); }
                }
                float lf = (pxo>0)      ? b2f(rp[-1]) : 0.f;
                float rt = (pxo+16<WW)  ? b2f(rp[16]) : 0.f;
                float w0=w9[ky*3], w1=w9[ky*3+1], wv2=w9[ky*3+2];
                #pragma unroll
                for (int i=0;i<16;++i){
                    float l  = i ? m[i-1] : lf;
                    float r_ = (i==15) ? rt : m[i+1];
                    acc[i] = fmaf(w0,l, fmaf(w1,m[i], fmaf(wv2,r_,acc[i])));
                }
            }
            ushort8 o0, o1;
            #pragma unroll
            for (int i=0;i<8;++i){
                o0[i] = f2u(fgelu(acc[i]+bj));
                o1[i] = f2u(fgelu(acc[8+i]+bj));
            }
            *(ushort8*)(ub + cj*260 + pxo)     = o0;
            *(ushort8*)(ub + cj*260 + pxo + 8) = o1;
        }
        __syncthreads();
        // ---- lazy h2 (MFMA from xs) + gate: g overwrites u in place
        {
            bf16x8 A1g[2][2];
            #pragma unroll
            for (int t2=0;t2<2;++t2)
                #pragma unroll
                for (int kh=0;kh<2;++kh){
                    bf16x8 fb;
                    #pragma unroll
                    for (int j=0;j<8;++j){
                        int cin = kh*32 + g*8 + j;
                        fb[j] = (short)f2u(l1w[cin*256 + 128 + cc*32 + t2*16 + col]);
                    }
                    A1g[t2][kh]=fb;
                }
            #pragma unroll
            for (int q=0;q<2;++q){
                int px = (wv*2+q)*16 + col;
                bf16x8 B0 = *(const bf16x8*)((char*)xs + px*128 + ((g*16) ^ ((px&7)<<4)));
                bf16x8 B1 = *(const bf16x8*)((char*)xs + px*128 + ((64 + g*16) ^ ((px&7)<<4)));
                f32x4 D0 = *(const f32x4*)(l1b + 128 + cc*32 + g*4);
                f32x4 D1 = *(const f32x4*)(l1b + 128 + cc*32 + 16 + g*4);
                D0 = __builtin_amdgcn_mfma_f32_16x16x32_bf16(A1g[0][0], B0, D0, 0,0,0);
                D0 = __builtin_amdgcn_mfma_f32_16x16x32_bf16(A1g[0][1], B1, D0, 0,0,0);
                D1 = __builtin_amdgcn_mfma_f32_16x16x32_bf16(A1g[1][0], B0, D1, 0,0,0);
                D1 = __builtin_amdgcn_mfma_f32_16x16x32_bf16(A1g[1][1], B1, D1, 0,0,0);
                #pragma unroll
                for (int rr=0;rr<4;++rr){
                    int cj0 = g*4 + rr, cj1 = 16 + g*4 + rr;
                    float u0 = u2f(ub[cj0*260 + px]);
                    float u1 = u2f(ub[cj1*260 + px]);
                    ub[cj0*260 + px] = f2u(u0 * fgelu(D0[rr]));
                    ub[cj1*260 + px] = f2u(u1 * fgelu(D1[rr]));
                }
            }
        }
        __syncthreads();
        // ---- lin2 accumulation for this chunk (reads g from ub)
        {
            bf16x8 A2[4];
            #pragma unroll
            for (int ot=0;ot<4;++ot){
                bf16x8 f;
                #pragma unroll
                for (int j=0;j<8;++j){
                    int k = cc*32 + ((j>>2)<<4) + (g<<2) + (j&3);
                    f[j] = (short)f2u(w2[k*64 + ot*16 + col]);
                }
                A2[ot] = f;
            }
            #pragma unroll
            for (int q=0;q<2;++q){
                int px = (wv*2+q)*16 + col;
                bf16x8 Bg;
                #pragma unroll
                for (int j=0;j<8;++j){
                    int cjj = ((j>>2)<<4) + (g<<2) + (j&3);
                    Bg[j] = (short)ub[cjj*260 + px];
                }
                #pragma unroll
                for (int ot=0;ot<4;++ot)
                    Dx[q][ot] = __builtin_amdgcn_mfma_f32_16x16x32_bf16(A2[ot], Bg, Dx[q][ot], 0,0,0);
            }
        }
        __syncthreads();
    }
    // ---- epilogue: + residual v, write x (and x+x_init last layer)
    #pragma unroll
    for (int q=0;q<2;++q)
        #pragma unroll
        for (int ot=0;ot<4;++ot)
            #pragma unroll
            for (int rr=0;rr<4;++rr){
                int ch = ot*16 + g*4 + rr;
                size_t off = ((size_t)(b*CC + ch))*HWS + (size_t)y*WW + (wv*2+q)*16 + col;
                float rv = Dx[q][ot][rr] + b2f(v[off]);
                *reinterpret_cast<unsigned short*>(xout + off) = f2u(rv);
                if (xinit){
                    float s = rv + xinit[off];
                    *reinterpret_cast<unsigned short*>(xsum + off) = f2u(s);
                }
            }
}

// ---------------------------------------------------------------- final conv (64->1, 3x3), 4 px/thread
__global__ __launch_bounds__(256) void k_final(
    const bf16* __restrict__ s, const float* __restrict__ w,
    const float* __restrict__ bias, float* __restrict__ out)
{
    int gid = blockIdx.x*256 + threadIdx.x;
    int b = gid >> 12;
    int sp4 = (gid & 4095) << 2;
    int y = sp4 >> 7, x0 = sp4 & 127;
    const bf16* sb = s + (size_t)b*CC*HWS;
    float acc[4];
    #pragma unroll
    for (int i=0;i<4;++i) acc[i] = bias[0];

    #pragma unroll 1
    for (int c=0;c<CC;++c){
        const bf16* ip = sb + (size_t)c*HWS;
        const float* wp = w + (size_t)c*9;
        #pragma unroll
        for (int ky=0;ky<3;++ky){
            int yy = y + ky - 1;
            float xv[6];
            if (yy >= 0 && yy < HH){
                const bf16* rp = ip + yy*WW + x0;
                ushort4v mv = *reinterpret_cast<const ushort4v*>(rp);
                xv[1]=u2f(mv[0]); xv[2]=u2f(mv[1]); xv[3]=u2f(mv[2]); xv[4]=u2f(mv[3]);
                xv[0] = (x0>0)    ? b2f(rp[-1]) : 0.f;
                xv[5] = (x0+4<WW) ? b2f(rp[4])  : 0.f;
            } else {
                #pragma unroll
                for (int i=0;i<6;++i) xv[i] = 0.f;
            }
            float w0 = wp[ky*3+0], w1 = wp[ky*3+1], w2 = wp[ky*3+2];
            #pragma unroll
            for (int i=0;i<4;++i)
                acc[i] = fmaf(w0, xv[i],
                         fmaf(w1, xv[i+1],
                         fmaf(w2, xv[i+2], acc[i])));
        }
    }
    float4v ov; ov.x=acc[0]; ov.y=acc[1]; ov.z=acc[2]; ov.w=acc[3];
    *reinterpret_cast<float4v*>(out + (size_t)gid*4) = ov;
}

// ---------------------------------------------------------------- launch
extern "C" void kernel_launch(void* const* d_in, const int* in_sizes, int n_in,
                              void* d_out, int out_size, void* d_ws, size_t ws_size,
                              hipStream_t stream)
{
    const float* x    = (const float*)d_in[0];
    const float* wz1  = (const float*)d_in[1];
    const float* bz1  = (const float*)d_in[2];
    const float* wz2  = (const float*)d_in[3];
    const float* bz2  = (const float*)d_in[4];
    const float* wf1  = (const float*)d_in[5];
    const float* bf1  = (const float*)d_in[6];
    const float* wf2  = (const float*)d_in[7];
    const float* bf2  = (const float*)d_in[8];
    const float* pw   = (const float*)d_in[9];
    const float* l1w  = (const float*)d_in[10];
    const float* l1b  = (const float*)d_in[11];
    const float* dww  = (const float*)d_in[12];
    const float* dwb  = (const float*)d_in[13];
    const float* l2w  = (const float*)d_in[14];
    const float* l2b  = (const float*)d_in[15];
    const float* ow   = (const float*)d_in[16];
    const float* obb  = (const float*)d_in[17];

    char* ws = (char*)d_ws;
    bf16* xc    = (bf16*)(ws);                    // 33,554,432 B
    bf16* v     = (bf16*)(ws + 33554432);         // 33,554,432 B
    bf16* x1    = (bf16*)(ws + 67108864);         //  8,388,608 B
    bf16* xsumb = (bf16*)(ws + 75497472);         // 33,554,432 B
    bf16* h1buf = (bf16*)(ws + 109051904);        // 67,108,864 B (total ~176 MB)

    for (int l=0;l<3;++l){
        if (l == 0)
            k_gate<1><<<512, 256, 0, stream>>>(x, nullptr,
                wz1 + l*CC*CC, bz1 + l*CC, wz2 + l*CC*CC, bz2 + l*CC,
                wf1 + l*CC*CC, bf1 + l*CC, wf2 + l*CC*CC, bf2 + l*CC, v);
        else
            k_gate<0><<<512, 256, 0, stream>>>(nullptr, xc,
                wz1 + l*CC*CC, bz1 + l*CC, wz2 + l*CC*CC, bz2 + l*CC,
                wf1 + l*CC*CC, bf1 + l*CC, wf2 + l*CC*CC, bf2 + l*CC, v);
        k_pconv<<<NPIX/(256*4), 256, 0, stream>>>(v, pw + l*DCC*DCC*9, x1);
        k_lin1h<<<NPIX/256, 256, 0, stream>>>(x1, v,
                l1w + l*CC*256, l1b + l*256, h1buf);
        k_dwA  <<<BB*HH, 256, 0, stream>>>(x1, v, h1buf,
                l1w + l*CC*256, l1b + l*256,
                dww + l*HIDN*9, dwb + l*HIDN,
                l2w + l*HIDN*CC, l2b + l*CC,
                xc, (l==2) ? x : nullptr, xsumb);
    }
    k_final<<<NPIX/(256*4), 256, 0, stream>>>(xsumb, ow, obb, (float*)d_out);
}

// Round 12
// 825.011 us; speedup vs baseline: 1.2602x; 1.0435x over previous
//
#include <hip/hip_runtime.h>
#include <hip/hip_bf16.h>

#define CC 64
#define HIDN 128
#define DCC 16
#define HH 128
#define WW 128
#define HWS (HH*WW)        // 16384
#define BB 16
#define NPIX (BB*HWS)      // 262144

typedef __hip_bfloat16 bf16;
typedef __attribute__((ext_vector_type(8))) unsigned short ushort8;
typedef __attribute__((ext_vector_type(4))) unsigned short ushort4v;
typedef __attribute__((ext_vector_type(4))) float float4v;
typedef __attribute__((ext_vector_type(8))) short bf16x8;
typedef __attribute__((ext_vector_type(4))) float f32x4;

__device__ __forceinline__ float rcp_fast(float x){ return __builtin_amdgcn_rcpf(x); }
__device__ __forceinline__ float ftanh(float x){
    float e = __expf(2.f*x);
    return 1.f - 2.f*rcp_fast(e + 1.f);
}
__device__ __forceinline__ float fsig(float x){
    return rcp_fast(1.f + __expf(-x));
}
__device__ __forceinline__ float fgelu(float x){
    return x * fsig(x*(1.5957691216f + 0.07135481283f*x*x));
}
__device__ __forceinline__ float b2f(bf16 v){ return __bfloat162float(v); }
__device__ __forceinline__ float u2f(unsigned short u){
    unsigned v = ((unsigned)u) << 16; return __uint_as_float(v);
}
__device__ __forceinline__ unsigned short f2u(float f){
    bf16 h = __float2bfloat16(f);
    return *reinterpret_cast<unsigned short*>(&h);
}
__device__ __forceinline__ bf16x8 packf(float4v a, float4v b){
    bf16x8 r;
    r[0]=(short)f2u(a.x); r[1]=(short)f2u(a.y); r[2]=(short)f2u(a.z); r[3]=(short)f2u(a.w);
    r[4]=(short)f2u(b.x); r[5]=(short)f2u(b.y); r[6]=(short)f2u(b.z); r[7]=(short)f2u(b.w);
    return r;
}

// ---------------------------------------------------------------- gate (MFMA, LDS-staged x, zero-shuffle chain)
template<int F32>
__global__ __launch_bounds__(256,2) void k_gate(
    const float* __restrict__ xf, const bf16* __restrict__ xb,
    const float* __restrict__ wz1, const float* __restrict__ bz1,
    const float* __restrict__ wz2, const float* __restrict__ bz2,
    const float* __restrict__ wf1, const float* __restrict__ bf1,
    const float* __restrict__ wf2, const float* __restrict__ bf2,
    bf16* __restrict__ vout)
{
    __shared__ __align__(16) unsigned short xs[512*64];   // 64 KB
    const int t = threadIdx.x;
    const int lane = t & 63;
    const int wv = t >> 6;
    const int col = lane & 15;
    const int g = lane >> 4;
    const int blk = blockIdx.x;
    const int b = blk >> 5;
    const int sp0 = (blk & 31) << 9;

    {
        const int ch = t & 63;
        const int wg = t >> 6;
        const size_t base = ((size_t)b*CC + ch)*HWS + sp0;
        #pragma unroll
        for (int i=0;i<16;++i){
            int bufpx = (wg*16 + i) << 3;
            ushort8 val;
            if (F32){
                float4v a = *reinterpret_cast<const float4v*>(xf + base + bufpx);
                float4v c = *reinterpret_cast<const float4v*>(xf + base + bufpx + 4);
                val[0]=f2u(a.x); val[1]=f2u(a.y); val[2]=f2u(a.z); val[3]=f2u(a.w);
                val[4]=f2u(c.x); val[5]=f2u(c.y); val[6]=f2u(c.z); val[7]=f2u(c.w);
            } else {
                val = *reinterpret_cast<const ushort8*>(xb + base + bufpx);
            }
            #pragma unroll
            for (int j=0;j<8;++j){
                int px = bufpx + j;
                *(unsigned short*)((char*)xs + px*128 + ((ch*2) ^ ((px&7)<<4))) = val[j];
            }
        }
    }

    bf16x8 Az1[4][2], Af1[4][2], Az2[4][2], Af2[4][2];
    #pragma unroll
    for (int ot=0; ot<4; ++ot){
        #pragma unroll
        for (int kh=0; kh<2; ++kh){
            const float* p;
            p = wz1 + (ot*16+col)*64 + kh*32 + g*8;
            Az1[ot][kh] = packf(*(const float4v*)p, *(const float4v*)(p+4));
            p = wf1 + (ot*16+col)*64 + kh*32 + g*8;
            Af1[ot][kh] = packf(*(const float4v*)p, *(const float4v*)(p+4));
            p = wz2 + (ot*16+col)*64 + kh*32 + g*4;
            Az2[ot][kh] = packf(*(const float4v*)p, *(const float4v*)(p+16));
            p = wf2 + (ot*16+col)*64 + kh*32 + g*4;
            Af2[ot][kh] = packf(*(const float4v*)p, *(const float4v*)(p+16));
        }
    }
    __syncthreads();

    bf16* vb = vout + (size_t)b*CC*HWS;

    for (int it = wv; it < 32; it += 4){
        const int lpx = it*16 + col;
        const int px = sp0 + lpx;
        bf16x8 Bx[2];
        Bx[0] = *(const bf16x8*)((char*)xs + lpx*128 + ((g*16) ^ ((lpx&7)<<4)));
        Bx[1] = *(const bf16x8*)((char*)xs + lpx*128 + ((64 + g*16) ^ ((lpx&7)<<4)));
        f32x4 Dz[4], Df[4];
        #pragma unroll
        for (int ot=0; ot<4; ++ot){
            Dz[ot] = *(const f32x4*)(bz1 + ot*16 + g*4);
            Df[ot] = *(const f32x4*)(bf1 + ot*16 + g*4);
        }
        #pragma unroll
        for (int kh=0; kh<2; ++kh)
            #pragma unroll
            for (int ot=0; ot<4; ++ot){
                Dz[ot] = __builtin_amdgcn_mfma_f32_16x16x32_bf16(Az1[ot][kh], Bx[kh], Dz[ot], 0,0,0);
                Df[ot] = __builtin_amdgcn_mfma_f32_16x16x32_bf16(Af1[ot][kh], Bx[kh], Df[ot], 0,0,0);
            }
        #pragma unroll
        for (int ot=0; ot<4; ++ot)
            #pragma unroll
            for (int r=0; r<4; ++r){
                Dz[ot][r] = ftanh(Dz[ot][r]);
                Df[ot][r] = ftanh(Df[ot][r]);
            }
        bf16x8 Bz[2], Bf[2];
        #pragma unroll
        for (int kh=0; kh<2; ++kh)
            #pragma unroll
            for (int j=0; j<4; ++j){
                Bz[kh][j]   = (short)f2u(Dz[2*kh][j]);
                Bz[kh][4+j] = (short)f2u(Dz[2*kh+1][j]);
                Bf[kh][j]   = (short)f2u(Df[2*kh][j]);
                Bf[kh][4+j] = (short)f2u(Df[2*kh+1][j]);
            }
        f32x4 Ez[4], Ef[4];
        #pragma unroll
        for (int ot=0; ot<4; ++ot){
            Ez[ot] = *(const f32x4*)(bz2 + ot*16 + g*4);
            Ef[ot] = *(const f32x4*)(bf2 + ot*16 + g*4);
        }
        #pragma unroll
        for (int kh=0; kh<2; ++kh)
            #pragma unroll
            for (int ot=0; ot<4; ++ot){
                Ez[ot] = __builtin_amdgcn_mfma_f32_16x16x32_bf16(Az2[ot][kh], Bz[kh], Ez[ot], 0,0,0);
                Ef[ot] = __builtin_amdgcn_mfma_f32_16x16x32_bf16(Af2[ot][kh], Bf[kh], Ef[ot], 0,0,0);
            }
        #pragma unroll
        for (int ot=0; ot<4; ++ot)
            #pragma unroll
            for (int r=0; r<4; ++r){
                float Zv = ftanh(Ez[ot][r]);
                float Fv = fsig(Ef[ot][r]);
                *reinterpret_cast<unsigned short*>(vb + (size_t)(ot*16+g*4+r)*HWS + px)
                    = f2u((1.f - Fv)*Zv);
            }
    }
}

// ---------------------------------------------------------------- pconv (16->16, 3x3), 4 px/thread, XCD-swizzled
__global__ __launch_bounds__(256) void k_pconv(
    const bf16* __restrict__ v, const float* __restrict__ w, bf16* __restrict__ x1)
{
    int blk0 = blockIdx.x;                        // 256 blocks
    int blk = (blk0 & 7)*32 + (blk0 >> 3);        // XCD-contiguous
    int gid = blk*256 + threadIdx.x;
    int b = gid >> 12;
    int sp4 = (gid & 4095) << 2;
    int y = sp4 >> 7, x0 = sp4 & 127;
    const bf16* vb = v + (size_t)b*CC*HWS;
    float acc[DCC][4];
    #pragma unroll
    for (int o=0;o<DCC;++o)
        #pragma unroll
        for (int i=0;i<4;++i) acc[o][i] = 0.f;

    #pragma unroll 1
    for (int ic=0; ic<DCC; ++ic){
        const bf16* ip = vb + (size_t)ic*HWS;
        float xv[3][6];
        #pragma unroll
        for (int ky=0;ky<3;++ky){
            int yy = y + ky - 1;
            if (yy >= 0 && yy < HH){
                const bf16* rp = ip + yy*WW + x0;
                ushort4v mv = *reinterpret_cast<const ushort4v*>(rp);
                xv[ky][1]=u2f(mv[0]); xv[ky][2]=u2f(mv[1]);
                xv[ky][3]=u2f(mv[2]); xv[ky][4]=u2f(mv[3]);
                xv[ky][0] = (x0>0)     ? b2f(rp[-1]) : 0.f;
                xv[ky][5] = (x0+4<WW)  ? b2f(rp[4])  : 0.f;
            } else {
                #pragma unroll
                for (int i=0;i<6;++i) xv[ky][i] = 0.f;
            }
        }
        #pragma unroll
        for (int o=0;o<DCC;++o){
            const float* wp = w + (size_t)(o*DCC+ic)*9;
            #pragma unroll
            for (int ky=0;ky<3;++ky){
                float w0 = wp[ky*3+0], w1 = wp[ky*3+1], w2 = wp[ky*3+2];
                #pragma unroll
                for (int i=0;i<4;++i)
                    acc[o][i] = fmaf(w0, xv[ky][i],
                                fmaf(w1, xv[ky][i+1],
                                fmaf(w2, xv[ky][i+2], acc[o][i])));
            }
        }
    }
    bf16* xo = x1 + (size_t)b*DCC*HWS + sp4;
    #pragma unroll
    for (int o=0;o<DCC;++o){
        ushort4v ov;
        #pragma unroll
        for (int i=0;i<4;++i) ov[i] = f2u(acc[o][i]);
        *reinterpret_cast<ushort4v*>(xo + (size_t)o*HWS) = ov;
    }
}

// ---------------------------------------------------------------- lin1h: h1 = gelu(lin1_h(xcat)), computed ONCE per px.
__global__ __launch_bounds__(256) void k_lin1h(
    const bf16* __restrict__ x1, const bf16* __restrict__ v,
    const float* __restrict__ l1w, const float* __restrict__ l1b,
    bf16* __restrict__ h1out)
{
    __shared__ __align__(16) unsigned short xs[256*64];   // 32 KB
    __shared__ __align__(16) unsigned short tr[4][32*66]; // 16.5 KB, wave-private
    const int t = threadIdx.x;
    const int lane = t & 63;
    const int wv = t >> 6;
    const int col = lane & 15;
    const int g = lane >> 4;
    const int blk = blockIdx.x;         // 1024 blocks
    const int b = blk >> 6;
    const int sp0 = (blk & 63) << 8;

    {
        const int ch = t & 63;
        const int wg = t >> 6;
        const bf16* src = (ch < DCC) ? x1 + ((size_t)b*DCC + ch)*HWS
                                     : v  + ((size_t)b*CC  + ch)*HWS;
        #pragma unroll
        for (int i=0;i<8;++i){
            int bufpx = (wg*8 + i) << 3;
            ushort8 val = *reinterpret_cast<const ushort8*>(src + sp0 + bufpx);
            #pragma unroll
            for (int j=0;j<8;++j){
                int px = bufpx + j;
                *(unsigned short*)((char*)xs + px*128 + ((ch*2) ^ ((px&7)<<4))) = val[j];
            }
        }
    }
    __syncthreads();

    unsigned short* trw = &tr[wv][0];
    const int lpx0 = wv*64;

    #pragma unroll 1
    for (int oc=0; oc<4; ++oc){
        bf16x8 A1[2][2];
        #pragma unroll
        for (int t2=0;t2<2;++t2)
            #pragma unroll
            for (int kh=0;kh<2;++kh){
                bf16x8 fa;
                #pragma unroll
                for (int j=0;j<8;++j){
                    int cin = kh*32 + g*8 + j;
                    fa[j] = (short)f2u(l1w[cin*256 + oc*32 + t2*16 + col]);
                }
                A1[t2][kh]=fa;
            }
        #pragma unroll
        for (int lt=0;lt<4;++lt){
            int px = lpx0 + lt*16 + col;
            bf16x8 B0 = *(const bf16x8*)((char*)xs + px*128 + ((g*16) ^ ((px&7)<<4)));
            bf16x8 B1 = *(const bf16x8*)((char*)xs + px*128 + ((64 + g*16) ^ ((px&7)<<4)));
            f32x4 D0 = *(const f32x4*)(l1b + oc*32 + g*4);
            f32x4 D1 = *(const f32x4*)(l1b + oc*32 + 16 + g*4);
            D0 = __builtin_amdgcn_mfma_f32_16x16x32_bf16(A1[0][0], B0, D0, 0,0,0);
            D0 = __builtin_amdgcn_mfma_f32_16x16x32_bf16(A1[0][1], B1, D0, 0,0,0);
            D1 = __builtin_amdgcn_mfma_f32_16x16x32_bf16(A1[1][0], B0, D1, 0,0,0);
            D1 = __builtin_amdgcn_mfma_f32_16x16x32_bf16(A1[1][1], B1, D1, 0,0,0);
            int lp = lt*16 + col;
            #pragma unroll
            for (int rr=0;rr<4;++rr){
                trw[(g*4+rr)*66 + lp]    = f2u(fgelu(D0[rr]));
                trw[(16+g*4+rr)*66 + lp] = f2u(fgelu(D1[rr]));
            }
        }
        {
            int ch2 = lane >> 1;
            int half = lane & 1;
            const unsigned short* srcp = trw + ch2*66 + half*32;
            bf16* dst = h1out + ((size_t)(b*HIDN + oc*32 + ch2))*HWS + sp0 + lpx0 + half*32;
            #pragma unroll
            for (int i=0;i<4;++i){
                ushort8 u8 = *reinterpret_cast<const ushort8*>(srcp + i*8);
                *reinterpret_cast<ushort8*>(dst + i*8) = u8;
            }
        }
    }
}

// ---------------------------------------------------------------- dwA: dwconv(h1)+gelu + lazy-h2 + gate + lin2 fused in-register
// 1 row/block, 256 thr, XCD-swizzled (contiguous y-range per XCD -> h1 halo L2 hits).
// Gate folded into lin2: h2's D-layout slot == lin2's Bg psi2 slot for the SAME lane,
// so g = u * gelu(h2) goes straight into the MFMA B operand (R11 post-mortem:
// 12 barriers + ub write-back round trip; now 8 barriers, no write-back).
__global__ __launch_bounds__(256) void k_dwA(
    const bf16* __restrict__ x1, const bf16* __restrict__ v,
    const bf16* __restrict__ h1,
    const float* __restrict__ l1w, const float* __restrict__ l1b,
    const float* __restrict__ dww, const float* __restrict__ dwb,
    const float* __restrict__ w2,  const float* __restrict__ l2b,
    bf16* __restrict__ xout,
    const float* __restrict__ xinit,   // non-null on last layer
    bf16* __restrict__ xsum)
{
    __shared__ __align__(16) unsigned short xs[128*64];   // 16 KB (center row)
    __shared__ __align__(16) unsigned short ub[32*260];   // 16.6 KB (u per chunk)
    const int t = threadIdx.x;
    const int lane = t & 63;
    const int wv = t >> 6;
    const int col = lane & 15;
    const int g = lane >> 4;
    const int blk0 = blockIdx.x;          // 2048 blocks
    const int blk = (blk0 & 7)*256 + (blk0 >> 3);   // XCD-contiguous rows
    const int b = blk >> 7;
    const int y = blk & 127;

    {   // stage x-cat center row: 64ch x 128px
        const int ch = t & 63;
        const int wg = t >> 6;
        const bf16* src = (ch < DCC) ? x1 + ((size_t)b*DCC + ch)*HWS
                                     : v  + ((size_t)b*CC  + ch)*HWS;
        #pragma unroll
        for (int i=0;i<2;++i){
            int bufpx = (wg*2 + i) << 3;
            ushort8 val = *reinterpret_cast<const ushort8*>(src + (size_t)y*WW + bufpx);
            #pragma unroll
            for (int j=0;j<8;++j){
                int px = bufpx + j;
                *(unsigned short*)((char*)xs + px*128 + ((ch*2) ^ ((px&7)<<4))) = val[j];
            }
        }
    }
    __syncthreads();

    f32x4 Dx[2][4];
    #pragma unroll
    for (int q=0;q<2;++q)
        #pragma unroll
        for (int ot=0;ot<4;++ot)
            Dx[q][ot] = *(const f32x4*)(l2b + ot*16 + g*4);

    const int cj  = (t>>3) & 31;     // dw channel within chunk
    const int pxo = (t & 7) << 4;    // dw 16-px group

    #pragma unroll 1
    for (int cc=0; cc<4; ++cc){
        // ---- dw conv from global h1 (rows y-1..y+1) -> u in LDS
        {
            int chg = cc*32 + cj;
            const bf16* h1p = h1 + ((size_t)(b*HIDN + chg))*HWS;
            float w9[9];
            #pragma unroll
            for (int i=0;i<9;++i) w9[i] = dww[chg*9+i];
            float bj = dwb[chg];
            float acc[16];
            #pragma unroll
            for (int i=0;i<16;++i) acc[i]=0.f;
            #pragma unroll
            for (int ky=0; ky<3; ++ky){
                int gy = y + ky - 1;
                if (gy < 0 || gy >= HH) continue;
                const bf16* rp = h1p + (size_t)gy*WW + pxo;
                float m[16];
                {
                    ushort8 a = *reinterpret_cast<const ushort8*>(rp);
                    ushort8 c = *reinterpret_cast<const ushort8*>(rp+8);
                    #pragma unroll
                    for (int i=0;i<8;++i){ m[i]=u2f(a[i]); m[8+i]=u2f(c[i]); }
                }
                float lf = (pxo>0)      ? b2f(rp[-1]) : 0.f;
                float rt = (pxo+16<WW)  ? b2f(rp[16]) : 0.f;
                float w0=w9[ky*3], w1=w9[ky*3+1], wv2=w9[ky*3+2];
                #pragma unroll
                for (int i=0;i<16;++i){
                    float l  = i ? m[i-1] : lf;
                    float r_ = (i==15) ? rt : m[i+1];
                    acc[i] = fmaf(w0,l, fmaf(w1,m[i], fmaf(wv2,r_,acc[i])));
                }
            }
            ushort8 o0, o1;
            #pragma unroll
            for (int i=0;i<8;++i){
                o0[i] = f2u(fgelu(acc[i]+bj));
                o1[i] = f2u(fgelu(acc[8+i]+bj));
            }
            *(ushort8*)(ub + cj*260 + pxo)     = o0;
            *(ushort8*)(ub + cj*260 + pxo + 8) = o1;
        }
        __syncthreads();
        // ---- fused: lazy h2 MFMA + gate (in-reg) + lin2 MFMA
        {
            bf16x8 A1g[2][2];
            #pragma unroll
            for (int t2=0;t2<2;++t2)
                #pragma unroll
                for (int kh=0;kh<2;++kh){
                    bf16x8 fb;
                    #pragma unroll
                    for (int j=0;j<8;++j){
                        int cin = kh*32 + g*8 + j;
                        fb[j] = (short)f2u(l1w[cin*256 + 128 + cc*32 + t2*16 + col]);
                    }
                    A1g[t2][kh]=fb;
                }
            bf16x8 A2[4];
            #pragma unroll
            for (int ot=0;ot<4;++ot){
                bf16x8 f;
                #pragma unroll
                for (int j=0;j<8;++j){
                    int k = cc*32 + ((j>>2)<<4) + (g<<2) + (j&3);
                    f[j] = (short)f2u(w2[k*64 + ot*16 + col]);
                }
                A2[ot] = f;
            }
            #pragma unroll
            for (int q=0;q<2;++q){
                int px = (wv*2+q)*16 + col;
                bf16x8 B0 = *(const bf16x8*)((char*)xs + px*128 + ((g*16) ^ ((px&7)<<4)));
                bf16x8 B1 = *(const bf16x8*)((char*)xs + px*128 + ((64 + g*16) ^ ((px&7)<<4)));
                f32x4 D0 = *(const f32x4*)(l1b + 128 + cc*32 + g*4);
                f32x4 D1 = *(const f32x4*)(l1b + 128 + cc*32 + 16 + g*4);
                D0 = __builtin_amdgcn_mfma_f32_16x16x32_bf16(A1g[0][0], B0, D0, 0,0,0);
                D0 = __builtin_amdgcn_mfma_f32_16x16x32_bf16(A1g[0][1], B1, D0, 0,0,0);
                D1 = __builtin_amdgcn_mfma_f32_16x16x32_bf16(A1g[1][0], B0, D1, 0,0,0);
                D1 = __builtin_amdgcn_mfma_f32_16x16x32_bf16(A1g[1][1], B1, D1, 0,0,0);
                bf16x8 Bg;
                #pragma unroll
                for (int j=0;j<4;++j){
                    float u0 = u2f(ub[(g*4+j)*260 + px]);
                    float u1 = u2f(ub[(16+g*4+j)*260 + px]);
                    Bg[j]   = (short)f2u(u0 * fgelu(D0[j]));
                    Bg[4+j] = (short)f2u(u1 * fgelu(D1[j]));
                }
                #pragma unroll
                for (int ot=0;ot<4;++ot)
                    Dx[q][ot] = __builtin_amdgcn_mfma_f32_16x16x32_bf16(A2[ot], Bg, Dx[q][ot], 0,0,0);
            }
        }
        __syncthreads();
    }
    // ---- epilogue: + residual v, write x (and x+x_init last layer)
    #pragma unroll
    for (int q=0;q<2;++q)
        #pragma unroll
        for (int ot=0;ot<4;++ot)
            #pragma unroll
            for (int rr=0;rr<4;++rr){
                int ch = ot*16 + g*4 + rr;
                size_t off = ((size_t)(b*CC + ch))*HWS + (size_t)y*WW + (wv*2+q)*16 + col;
                float rv = Dx[q][ot][rr] + b2f(v[off]);
                *reinterpret_cast<unsigned short*>(xout + off) = f2u(rv);
                if (xinit){
                    float s = rv + xinit[off];
                    *reinterpret_cast<unsigned short*>(xsum + off) = f2u(s);
                }
            }
}

// ---------------------------------------------------------------- final conv (64->1, 3x3), 4 px/thread
__global__ __launch_bounds__(256) void k_final(
    const bf16* __restrict__ s, const float* __restrict__ w,
    const float* __restrict__ bias, float* __restrict__ out)
{
    int gid = blockIdx.x*256 + threadIdx.x;
    int b = gid >> 12;
    int sp4 = (gid & 4095) << 2;
    int y = sp4 >> 7, x0 = sp4 & 127;
    const bf16* sb = s + (size_t)b*CC*HWS;
    float acc[4];
    #pragma unroll
    for (int i=0;i<4;++i) acc[i] = bias[0];

    #pragma unroll 1
    for (int c=0;c<CC;++c){
        const bf16* ip = sb + (size_t)c*HWS;
        const float* wp = w + (size_t)c*9;
        #pragma unroll
        for (int ky=0;ky<3;++ky){
            int yy = y + ky - 1;
            float xv[6];
            if (yy >= 0 && yy < HH){
                const bf16* rp = ip + yy*WW + x0;
                ushort4v mv = *reinterpret_cast<const ushort4v*>(rp);
                xv[1]=u2f(mv[0]); xv[2]=u2f(mv[1]); xv[3]=u2f(mv[2]); xv[4]=u2f(mv[3]);
                xv[0] = (x0>0)    ? b2f(rp[-1]) : 0.f;
                xv[5] = (x0+4<WW) ? b2f(rp[4])  : 0.f;
            } else {
                #pragma unroll
                for (int i=0;i<6;++i) xv[i] = 0.f;
            }
            float w0 = wp[ky*3+0], w1 = wp[ky*3+1], w2 = wp[ky*3+2];
            #pragma unroll
            for (int i=0;i<4;++i)
                acc[i] = fmaf(w0, xv[i],
                         fmaf(w1, xv[i+1],
                         fmaf(w2, xv[i+2], acc[i])));
        }
    }
    float4v ov; ov.x=acc[0]; ov.y=acc[1]; ov.z=acc[2]; ov.w=acc[3];
    *reinterpret_cast<float4v*>(out + (size_t)gid*4) = ov;
}

// ---------------------------------------------------------------- launch
extern "C" void kernel_launch(void* const* d_in, const int* in_sizes, int n_in,
                              void* d_out, int out_size, void* d_ws, size_t ws_size,
                              hipStream_t stream)
{
    const float* x    = (const float*)d_in[0];
    const float* wz1  = (const float*)d_in[1];
    const float* bz1  = (const float*)d_in[2];
    const float* wz2  = (const float*)d_in[3];
    const float* bz2  = (const float*)d_in[4];
    const float* wf1  = (const float*)d_in[5];
    const float* bf1  = (const float*)d_in[6];
    const float* wf2  = (const float*)d_in[7];
    const float* bf2  = (const float*)d_in[8];
    const float* pw   = (const float*)d_in[9];
    const float* l1w  = (const float*)d_in[10];
    const float* l1b  = (const float*)d_in[11];
    const float* dww  = (const float*)d_in[12];
    const float* dwb  = (const float*)d_in[13];
    const float* l2w  = (const float*)d_in[14];
    const float* l2b  = (const float*)d_in[15];
    const float* ow   = (const float*)d_in[16];
    const float* obb  = (const float*)d_in[17];

    char* ws = (char*)d_ws;
    bf16* xc    = (bf16*)(ws);                    // 33,554,432 B
    bf16* v     = (bf16*)(ws + 33554432);         // 33,554,432 B
    bf16* x1    = (bf16*)(ws + 67108864);         //  8,388,608 B
    bf16* xsumb = (bf16*)(ws + 75497472);         // 33,554,432 B
    bf16* h1buf = (bf16*)(ws + 109051904);        // 67,108,864 B (total ~176 MB)

    for (int l=0;l<3;++l){
        if (l == 0)
            k_gate<1><<<512, 256, 0, stream>>>(x, nullptr,
                wz1 + l*CC*CC, bz1 + l*CC, wz2 + l*CC*CC, bz2 + l*CC,
                wf1 + l*CC*CC, bf1 + l*CC, wf2 + l*CC*CC, bf2 + l*CC, v);
        else
            k_gate<0><<<512, 256, 0, stream>>>(nullptr, xc,
                wz1 + l*CC*CC, bz1 + l*CC, wz2 + l*CC*CC, bz2 + l*CC,
                wf1 + l*CC*CC, bf1 + l*CC, wf2 + l*CC*CC, bf2 + l*CC, v);
        k_pconv<<<NPIX/(256*4), 256, 0, stream>>>(v, pw + l*DCC*DCC*9, x1);
        k_lin1h<<<NPIX/256, 256, 0, stream>>>(x1, v,
                l1w + l*CC*256, l1b + l*256, h1buf);
        k_dwA  <<<BB*HH, 256, 0, stream>>>(x1, v, h1buf,
                l1w + l*CC*256, l1b + l*256,
                dww + l*HIDN*9, dwb + l*HIDN,
                l2w + l*HIDN*CC, l2b + l*CC,
                xc, (l==2) ? x : nullptr, xsumb);
    }
    k_final<<<NPIX/(256*4), 256, 0, stream>>>(xsumb, ow, obb, (float*)d_out);
}

// Round 13
// 743.753 us; speedup vs baseline: 1.3979x; 1.1093x over previous
//
#include <hip/hip_runtime.h>
#include <hip/hip_bf16.h>

#define CC 64
#define HIDN 128
#define DCC 16
#define HH 128
#define WW 128
#define HWS (HH*WW)        // 16384
#define BB 16
#define NPIX (BB*HWS)      // 262144

typedef __hip_bfloat16 bf16;
typedef __attribute__((ext_vector_type(8))) unsigned short ushort8;
typedef __attribute__((ext_vector_type(4))) unsigned short ushort4v;
typedef __attribute__((ext_vector_type(4))) float float4v;
typedef __attribute__((ext_vector_type(8))) short bf16x8;
typedef __attribute__((ext_vector_type(4))) float f32x4;

__device__ __forceinline__ float rcp_fast(float x){ return __builtin_amdgcn_rcpf(x); }
__device__ __forceinline__ float ftanh(float x){
    float e = __expf(2.f*x);
    return 1.f - 2.f*rcp_fast(e + 1.f);
}
__device__ __forceinline__ float fsig(float x){
    return rcp_fast(1.f + __expf(-x));
}
__device__ __forceinline__ float fgelu(float x){
    return x * fsig(x*(1.5957691216f + 0.07135481283f*x*x));
}
__device__ __forceinline__ float b2f(bf16 v){ return __bfloat162float(v); }
__device__ __forceinline__ float u2f(unsigned short u){
    unsigned v = ((unsigned)u) << 16; return __uint_as_float(v);
}
__device__ __forceinline__ unsigned short f2u(float f){
    bf16 h = __float2bfloat16(f);
    return *reinterpret_cast<unsigned short*>(&h);
}
__device__ __forceinline__ bf16x8 packf(float4v a, float4v b){
    bf16x8 r;
    r[0]=(short)f2u(a.x); r[1]=(short)f2u(a.y); r[2]=(short)f2u(a.z); r[3]=(short)f2u(a.w);
    r[4]=(short)f2u(b.x); r[5]=(short)f2u(b.y); r[6]=(short)f2u(b.z); r[7]=(short)f2u(b.w);
    return r;
}

// ---------------------------------------------------------------- gate (MFMA, LDS-staged x, zero-shuffle chain)
template<int F32>
__global__ __launch_bounds__(256,2) void k_gate(
    const float* __restrict__ xf, const bf16* __restrict__ xb,
    const float* __restrict__ wz1, const float* __restrict__ bz1,
    const float* __restrict__ wz2, const float* __restrict__ bz2,
    const float* __restrict__ wf1, const float* __restrict__ bf1,
    const float* __restrict__ wf2, const float* __restrict__ bf2,
    bf16* __restrict__ vout)
{
    __shared__ __align__(16) unsigned short xs[512*64];   // 64 KB
    const int t = threadIdx.x;
    const int lane = t & 63;
    const int wv = t >> 6;
    const int col = lane & 15;
    const int g = lane >> 4;
    const int blk = blockIdx.x;
    const int b = blk >> 5;
    const int sp0 = (blk & 31) << 9;

    {
        const int ch = t & 63;
        const int wg = t >> 6;
        const size_t base = ((size_t)b*CC + ch)*HWS + sp0;
        #pragma unroll
        for (int i=0;i<16;++i){
            int bufpx = (wg*16 + i) << 3;
            ushort8 val;
            if (F32){
                float4v a = *reinterpret_cast<const float4v*>(xf + base + bufpx);
                float4v c = *reinterpret_cast<const float4v*>(xf + base + bufpx + 4);
                val[0]=f2u(a.x); val[1]=f2u(a.y); val[2]=f2u(a.z); val[3]=f2u(a.w);
                val[4]=f2u(c.x); val[5]=f2u(c.y); val[6]=f2u(c.z); val[7]=f2u(c.w);
            } else {
                val = *reinterpret_cast<const ushort8*>(xb + base + bufpx);
            }
            #pragma unroll
            for (int j=0;j<8;++j){
                int px = bufpx + j;
                *(unsigned short*)((char*)xs + px*128 + ((ch*2) ^ ((px&7)<<4))) = val[j];
            }
        }
    }

    bf16x8 Az1[4][2], Af1[4][2], Az2[4][2], Af2[4][2];
    #pragma unroll
    for (int ot=0; ot<4; ++ot){
        #pragma unroll
        for (int kh=0; kh<2; ++kh){
            const float* p;
            p = wz1 + (ot*16+col)*64 + kh*32 + g*8;
            Az1[ot][kh] = packf(*(const float4v*)p, *(const float4v*)(p+4));
            p = wf1 + (ot*16+col)*64 + kh*32 + g*8;
            Af1[ot][kh] = packf(*(const float4v*)p, *(const float4v*)(p+4));
            p = wz2 + (ot*16+col)*64 + kh*32 + g*4;
            Az2[ot][kh] = packf(*(const float4v*)p, *(const float4v*)(p+16));
            p = wf2 + (ot*16+col)*64 + kh*32 + g*4;
            Af2[ot][kh] = packf(*(const float4v*)p, *(const float4v*)(p+16));
        }
    }
    __syncthreads();

    bf16* vb = vout + (size_t)b*CC*HWS;

    for (int it = wv; it < 32; it += 4){
        const int lpx = it*16 + col;
        const int px = sp0 + lpx;
        bf16x8 Bx[2];
        Bx[0] = *(const bf16x8*)((char*)xs + lpx*128 + ((g*16) ^ ((lpx&7)<<4)));
        Bx[1] = *(const bf16x8*)((char*)xs + lpx*128 + ((64 + g*16) ^ ((lpx&7)<<4)));
        f32x4 Dz[4], Df[4];
        #pragma unroll
        for (int ot=0; ot<4; ++ot){
            Dz[ot] = *(const f32x4*)(bz1 + ot*16 + g*4);
            Df[ot] = *(const f32x4*)(bf1 + ot*16 + g*4);
        }
        #pragma unroll
        for (int kh=0; kh<2; ++kh)
            #pragma unroll
            for (int ot=0; ot<4; ++ot){
                Dz[ot] = __builtin_amdgcn_mfma_f32_16x16x32_bf16(Az1[ot][kh], Bx[kh], Dz[ot], 0,0,0);
                Df[ot] = __builtin_amdgcn_mfma_f32_16x16x32_bf16(Af1[ot][kh], Bx[kh], Df[ot], 0,0,0);
            }
        #pragma unroll
        for (int ot=0; ot<4; ++ot)
            #pragma unroll
            for (int r=0; r<4; ++r){
                Dz[ot][r] = ftanh(Dz[ot][r]);
                Df[ot][r] = ftanh(Df[ot][r]);
            }
        bf16x8 Bz[2], Bf[2];
        #pragma unroll
        for (int kh=0; kh<2; ++kh)
            #pragma unroll
            for (int j=0; j<4; ++j){
                Bz[kh][j]   = (short)f2u(Dz[2*kh][j]);
                Bz[kh][4+j] = (short)f2u(Dz[2*kh+1][j]);
                Bf[kh][j]   = (short)f2u(Df[2*kh][j]);
                Bf[kh][4+j] = (short)f2u(Df[2*kh+1][j]);
            }
        f32x4 Ez[4], Ef[4];
        #pragma unroll
        for (int ot=0; ot<4; ++ot){
            Ez[ot] = *(const f32x4*)(bz2 + ot*16 + g*4);
            Ef[ot] = *(const f32x4*)(bf2 + ot*16 + g*4);
        }
        #pragma unroll
        for (int kh=0; kh<2; ++kh)
            #pragma unroll
            for (int ot=0; ot<4; ++ot){
                Ez[ot] = __builtin_amdgcn_mfma_f32_16x16x32_bf16(Az2[ot][kh], Bz[kh], Ez[ot], 0,0,0);
                Ef[ot] = __builtin_amdgcn_mfma_f32_16x16x32_bf16(Af2[ot][kh], Bf[kh], Ef[ot], 0,0,0);
            }
        #pragma unroll
        for (int ot=0; ot<4; ++ot)
            #pragma unroll
            for (int r=0; r<4; ++r){
                float Zv = ftanh(Ez[ot][r]);
                float Fv = fsig(Ef[ot][r]);
                *reinterpret_cast<unsigned short*>(vb + (size_t)(ot*16+g*4+r)*HWS + px)
                    = f2u((1.f - Fv)*Zv);
            }
    }
}

// ---------------------------------------------------------------- pconv (16->16, 3x3), 4 px/thread, XCD-swizzled
__global__ __launch_bounds__(256) void k_pconv(
    const bf16* __restrict__ v, const float* __restrict__ w, bf16* __restrict__ x1)
{
    int blk0 = blockIdx.x;                        // 256 blocks
    int blk = (blk0 & 7)*32 + (blk0 >> 3);        // XCD-contiguous
    int gid = blk*256 + threadIdx.x;
    int b = gid >> 12;
    int sp4 = (gid & 4095) << 2;
    int y = sp4 >> 7, x0 = sp4 & 127;
    const bf16* vb = v + (size_t)b*CC*HWS;
    float acc[DCC][4];
    #pragma unroll
    for (int o=0;o<DCC;++o)
        #pragma unroll
        for (int i=0;i<4;++i) acc[o][i] = 0.f;

    #pragma unroll 1
    for (int ic=0; ic<DCC; ++ic){
        const bf16* ip = vb + (size_t)ic*HWS;
        float xv[3][6];
        #pragma unroll
        for (int ky=0;ky<3;++ky){
            int yy = y + ky - 1;
            if (yy >= 0 && yy < HH){
                const bf16* rp = ip + yy*WW + x0;
                ushort4v mv = *reinterpret_cast<const ushort4v*>(rp);
                xv[ky][1]=u2f(mv[0]); xv[ky][2]=u2f(mv[1]);
                xv[ky][3]=u2f(mv[2]); xv[ky][4]=u2f(mv[3]);
                xv[ky][0] = (x0>0)     ? b2f(rp[-1]) : 0.f;
                xv[ky][5] = (x0+4<WW)  ? b2f(rp[4])  : 0.f;
            } else {
                #pragma unroll
                for (int i=0;i<6;++i) xv[ky][i] = 0.f;
            }
        }
        #pragma unroll
        for (int o=0;o<DCC;++o){
            const float* wp = w + (size_t)(o*DCC+ic)*9;
            #pragma unroll
            for (int ky=0;ky<3;++ky){
                float w0 = wp[ky*3+0], w1 = wp[ky*3+1], w2 = wp[ky*3+2];
                #pragma unroll
                for (int i=0;i<4;++i)
                    acc[o][i] = fmaf(w0, xv[ky][i],
                                fmaf(w1, xv[ky][i+1],
                                fmaf(w2, xv[ky][i+2], acc[o][i])));
            }
        }
    }
    bf16* xo = x1 + (size_t)b*DCC*HWS + sp4;
    #pragma unroll
    for (int o=0;o<DCC;++o){
        ushort4v ov;
        #pragma unroll
        for (int i=0;i<4;++i) ov[i] = f2u(acc[o][i]);
        *reinterpret_cast<ushort4v*>(xo + (size_t)o*HWS) = ov;
    }
}

// ---------------------------------------------------------------- lin1h: h1 = gelu(lin1_h(xcat)), computed ONCE per px.
__global__ __launch_bounds__(256) void k_lin1h(
    const bf16* __restrict__ x1, const bf16* __restrict__ v,
    const float* __restrict__ l1w, const float* __restrict__ l1b,
    bf16* __restrict__ h1out)
{
    __shared__ __align__(16) unsigned short xs[256*64];   // 32 KB
    __shared__ __align__(16) unsigned short tr[4][32*66]; // 16.5 KB, wave-private
    const int t = threadIdx.x;
    const int lane = t & 63;
    const int wv = t >> 6;
    const int col = lane & 15;
    const int g = lane >> 4;
    const int blk = blockIdx.x;         // 1024 blocks
    const int b = blk >> 6;
    const int sp0 = (blk & 63) << 8;

    {
        const int ch = t & 63;
        const int wg = t >> 6;
        const bf16* src = (ch < DCC) ? x1 + ((size_t)b*DCC + ch)*HWS
                                     : v  + ((size_t)b*CC  + ch)*HWS;
        #pragma unroll
        for (int i=0;i<8;++i){
            int bufpx = (wg*8 + i) << 3;
            ushort8 val = *reinterpret_cast<const ushort8*>(src + sp0 + bufpx);
            #pragma unroll
            for (int j=0;j<8;++j){
                int px = bufpx + j;
                *(unsigned short*)((char*)xs + px*128 + ((ch*2) ^ ((px&7)<<4))) = val[j];
            }
        }
    }
    __syncthreads();

    unsigned short* trw = &tr[wv][0];
    const int lpx0 = wv*64;

    #pragma unroll 1
    for (int oc=0; oc<4; ++oc){
        bf16x8 A1[2][2];
        #pragma unroll
        for (int t2=0;t2<2;++t2)
            #pragma unroll
            for (int kh=0;kh<2;++kh){
                bf16x8 fa;
                #pragma unroll
                for (int j=0;j<8;++j){
                    int cin = kh*32 + g*8 + j;
                    fa[j] = (short)f2u(l1w[cin*256 + oc*32 + t2*16 + col]);
                }
                A1[t2][kh]=fa;
            }
        #pragma unroll
        for (int lt=0;lt<4;++lt){
            int px = lpx0 + lt*16 + col;
            bf16x8 B0 = *(const bf16x8*)((char*)xs + px*128 + ((g*16) ^ ((px&7)<<4)));
            bf16x8 B1 = *(const bf16x8*)((char*)xs + px*128 + ((64 + g*16) ^ ((px&7)<<4)));
            f32x4 D0 = *(const f32x4*)(l1b + oc*32 + g*4);
            f32x4 D1 = *(const f32x4*)(l1b + oc*32 + 16 + g*4);
            D0 = __builtin_amdgcn_mfma_f32_16x16x32_bf16(A1[0][0], B0, D0, 0,0,0);
            D0 = __builtin_amdgcn_mfma_f32_16x16x32_bf16(A1[0][1], B1, D0, 0,0,0);
            D1 = __builtin_amdgcn_mfma_f32_16x16x32_bf16(A1[1][0], B0, D1, 0,0,0);
            D1 = __builtin_amdgcn_mfma_f32_16x16x32_bf16(A1[1][1], B1, D1, 0,0,0);
            int lp = lt*16 + col;
            #pragma unroll
            for (int rr=0;rr<4;++rr){
                trw[(g*4+rr)*66 + lp]    = f2u(fgelu(D0[rr]));
                trw[(16+g*4+rr)*66 + lp] = f2u(fgelu(D1[rr]));
            }
        }
        {
            int ch2 = lane >> 1;
            int half = lane & 1;
            const unsigned short* srcp = trw + ch2*66 + half*32;
            bf16* dst = h1out + ((size_t)(b*HIDN + oc*32 + ch2))*HWS + sp0 + lpx0 + half*32;
            #pragma unroll
            for (int i=0;i<4;++i){
                ushort8 u8 = *reinterpret_cast<const ushort8*>(srcp + i*8);
                *reinterpret_cast<ushort8*>(dst + i*8) = u8;
            }
        }
    }
}

// ---------------------------------------------------------------- dwA: dwconv(h1)+gelu + lazy-h2 + gate + lin2 fused
// R13: (1) h1 rows register-prefetched one chunk ahead (hide HBM latency across
// the MFMA phase); (2) weight fragments served from LDS-staged bf16 transposes
// (was 64 global f32 gathers per chunk on the critical path); (3) coalesced
// epilogue via LDS transpose. Geometry unchanged from R12 (proven correct).
__global__ __launch_bounds__(256) void k_dwA(
    const bf16* __restrict__ x1, const bf16* __restrict__ v,
    const bf16* __restrict__ h1,
    const float* __restrict__ l1w, const float* __restrict__ l1b,
    const float* __restrict__ dww, const float* __restrict__ dwb,
    const float* __restrict__ w2,  const float* __restrict__ l2b,
    bf16* __restrict__ xout,
    const float* __restrict__ xinit,   // non-null on last layer
    bf16* __restrict__ xsum)
{
    __shared__ __align__(16) unsigned short xs[128*64];    // 16 KB (center row)
    __shared__ __align__(16) unsigned short ub[64*136];    // 17 KB (u chunks / epilogue transpose)
    __shared__ __align__(16) unsigned short l1wt[128*68];  // 17 KB: [out 0..127][cin], h2-half of l1w
    __shared__ __align__(16) unsigned short w2t[64*132];   // 16.5 KB: [c][k]
    const int t = threadIdx.x;
    const int lane = t & 63;
    const int wv = t >> 6;
    const int col = lane & 15;
    const int g = lane >> 4;
    const int blk0 = blockIdx.x;          // 2048 blocks
    const int blk = (blk0 & 7)*256 + (blk0 >> 3);   // XCD-contiguous rows
    const int b = blk >> 7;
    const int y = blk & 127;

    const int cj  = (t>>3) & 31;     // dw channel within chunk
    const int pxo = (t & 7) << 4;    // dw 16-px group

    // ---- prefetch state (chunk-ahead registers)
    ushort8 pfa[3], pfb[3];
    unsigned short pfl[3], pfr[3];
    float pw9[9], pbj;
    auto LOADCHUNK = [&](int cc){
        int chg = cc*32 + cj;
        const bf16* h1p = h1 + ((size_t)(b*HIDN + chg))*HWS;
        #pragma unroll
        for (int ky=0; ky<3; ++ky){
            int gy = y + ky - 1;
            if (gy >= 0 && gy < HH){
                const bf16* rp = h1p + (size_t)gy*WW + pxo;
                pfa[ky] = *reinterpret_cast<const ushort8*>(rp);
                pfb[ky] = *reinterpret_cast<const ushort8*>(rp+8);
                pfl[ky] = (pxo>0)     ? *reinterpret_cast<const unsigned short*>(rp-1)  : 0;
                pfr[ky] = (pxo+16<WW) ? *reinterpret_cast<const unsigned short*>(rp+16) : 0;
            } else {
                #pragma unroll
                for (int i=0;i<8;++i){ pfa[ky][i]=0; pfb[ky][i]=0; }
                pfl[ky]=0; pfr[ky]=0;
            }
        }
        #pragma unroll
        for (int i=0;i<9;++i) pw9[i] = dww[chg*9+i];
        pbj = dwb[chg];
    };

    LOADCHUNK(0);   // earliest issue

    {   // stage x-cat center row: 64ch x 128px
        const int ch = t & 63;
        const int wg = t >> 6;
        const bf16* src = (ch < DCC) ? x1 + ((size_t)b*DCC + ch)*HWS
                                     : v  + ((size_t)b*CC  + ch)*HWS;
        #pragma unroll
        for (int i=0;i<2;++i){
            int bufpx = (wg*2 + i) << 3;
            ushort8 val = *reinterpret_cast<const ushort8*>(src + (size_t)y*WW + bufpx);
            #pragma unroll
            for (int j=0;j<8;++j){
                int px = bufpx + j;
                *(unsigned short*)((char*)xs + px*128 + ((ch*2) ^ ((px&7)<<4))) = val[j];
            }
        }
    }
    {   // stage l1wt: [out k 0..127][cin 0..63], bf16, from h2-half of l1w
        int cin = t >> 2;
        int o0  = (t & 3) * 32;
        const float* src = l1w + cin*256 + 128 + o0;
        #pragma unroll
        for (int i=0;i<32;i+=4){
            float4v f = *reinterpret_cast<const float4v*>(src + i);
            l1wt[(o0+i+0)*68 + cin] = f2u(f.x);
            l1wt[(o0+i+1)*68 + cin] = f2u(f.y);
            l1wt[(o0+i+2)*68 + cin] = f2u(f.z);
            l1wt[(o0+i+3)*68 + cin] = f2u(f.w);
        }
    }
    {   // stage w2t: [c 0..63][k 0..127], bf16
        int k  = t >> 1;
        int c0 = (t & 1) * 32;
        const float* src = w2 + k*64 + c0;
        #pragma unroll
        for (int i=0;i<32;i+=4){
            float4v f = *reinterpret_cast<const float4v*>(src + i);
            w2t[(c0+i+0)*132 + k] = f2u(f.x);
            w2t[(c0+i+1)*132 + k] = f2u(f.y);
            w2t[(c0+i+2)*132 + k] = f2u(f.z);
            w2t[(c0+i+3)*132 + k] = f2u(f.w);
        }
    }
    __syncthreads();

    f32x4 Dx[2][4];
    #pragma unroll
    for (int q=0;q<2;++q)
        #pragma unroll
        for (int ot=0;ot<4;++ot)
            Dx[q][ot] = *(const f32x4*)(l2b + ot*16 + g*4);

    #pragma unroll 1
    for (int cc=0; cc<4; ++cc){
        // ---- dw conv from prefetched regs -> u
        ushort8 o0v, o1v;
        {
            float acc[16];
            #pragma unroll
            for (int i=0;i<16;++i) acc[i]=0.f;
            #pragma unroll
            for (int ky=0; ky<3; ++ky){
                float m[16];
                #pragma unroll
                for (int i=0;i<8;++i){ m[i]=u2f(pfa[ky][i]); m[8+i]=u2f(pfb[ky][i]); }
                float lf = u2f(pfl[ky]);
                float rt = u2f(pfr[ky]);
                float w0=pw9[ky*3], w1=pw9[ky*3+1], wv2=pw9[ky*3+2];
                #pragma unroll
                for (int i=0;i<16;++i){
                    float l  = i ? m[i-1] : lf;
                    float r_ = (i==15) ? rt : m[i+1];
                    acc[i] = fmaf(w0,l, fmaf(w1,m[i], fmaf(wv2,r_,acc[i])));
                }
            }
            #pragma unroll
            for (int i=0;i<8;++i){
                o0v[i] = f2u(fgelu(acc[i]+pbj));
                o1v[i] = f2u(fgelu(acc[8+i]+pbj));
            }
        }
        // issue next chunk's loads now (in flight across barrier + MFMA phase)
        if (cc < 3) LOADCHUNK(cc+1);
        *(ushort8*)(ub + cj*260 + pxo)     = o0v;
        *(ushort8*)(ub + cj*260 + pxo + 8) = o1v;
        __syncthreads();
        // ---- fused: lazy h2 MFMA + gate (in-reg) + lin2 MFMA; frags from LDS
        {
            bf16x8 A1g[2][2];
            #pragma unroll
            for (int t2=0;t2<2;++t2)
                #pragma unroll
                for (int kh=0;kh<2;++kh){
                    const unsigned short* p = l1wt + (cc*32 + t2*16 + col)*68 + kh*32 + g*8;
                    ushort4v lo = *reinterpret_cast<const ushort4v*>(p);
                    ushort4v hi = *reinterpret_cast<const ushort4v*>(p+4);
                    bf16x8 f;
                    #pragma unroll
                    for (int j=0;j<4;++j){ f[j]=(short)lo[j]; f[4+j]=(short)hi[j]; }
                    A1g[t2][kh]=f;
                }
            bf16x8 A2[4];
            #pragma unroll
            for (int ot=0;ot<4;++ot){
                const unsigned short* p = w2t + (ot*16+col)*132 + cc*32 + (g<<2);
                ushort4v lo = *reinterpret_cast<const ushort4v*>(p);
                ushort4v hi = *reinterpret_cast<const ushort4v*>(p+16);
                bf16x8 f;
                #pragma unroll
                for (int j=0;j<4;++j){ f[j]=(short)lo[j]; f[4+j]=(short)hi[j]; }
                A2[ot] = f;
            }
            #pragma unroll
            for (int q=0;q<2;++q){
                int px = (wv*2+q)*16 + col;
                bf16x8 B0 = *(const bf16x8*)((char*)xs + px*128 + ((g*16) ^ ((px&7)<<4)));
                bf16x8 B1 = *(const bf16x8*)((char*)xs + px*128 + ((64 + g*16) ^ ((px&7)<<4)));
                f32x4 D0 = *(const f32x4*)(l1b + 128 + cc*32 + g*4);
                f32x4 D1 = *(const f32x4*)(l1b + 128 + cc*32 + 16 + g*4);
                D0 = __builtin_amdgcn_mfma_f32_16x16x32_bf16(A1g[0][0], B0, D0, 0,0,0);
                D0 = __builtin_amdgcn_mfma_f32_16x16x32_bf16(A1g[0][1], B1, D0, 0,0,0);
                D1 = __builtin_amdgcn_mfma_f32_16x16x32_bf16(A1g[1][0], B0, D1, 0,0,0);
                D1 = __builtin_amdgcn_mfma_f32_16x16x32_bf16(A1g[1][1], B1, D1, 0,0,0);
                bf16x8 Bg;
                #pragma unroll
                for (int j=0;j<4;++j){
                    float u0 = u2f(ub[(g*4+j)*260 + px]);
                    float u1 = u2f(ub[(16+g*4+j)*260 + px]);
                    Bg[j]   = (short)f2u(u0 * fgelu(D0[j]));
                    Bg[4+j] = (short)f2u(u1 * fgelu(D1[j]));
                }
                #pragma unroll
                for (int ot=0;ot<4;++ot)
                    Dx[q][ot] = __builtin_amdgcn_mfma_f32_16x16x32_bf16(A2[ot], Bg, Dx[q][ot], 0,0,0);
            }
        }
        __syncthreads();
    }
    // ---- epilogue: transpose Dx through ub (stride 136, 16B-aligned rows),
    //      then coalesced v-read + x-write (+ xsum for last layer)
    #pragma unroll
    for (int q=0;q<2;++q)
        #pragma unroll
        for (int ot=0;ot<4;++ot)
            #pragma unroll
            for (int rr=0;rr<4;++rr)
                ub[(ot*16 + g*4 + rr)*136 + (wv*2+q)*16 + col] = f2u(Dx[q][ot][rr]);
    __syncthreads();
    {
        int ch  = t >> 2;
        int pxb = (t & 3) * 32;
        size_t off = ((size_t)(b*CC + ch))*HWS + (size_t)y*WW + pxb;
        #pragma unroll
        for (int i=0;i<4;++i){
            ushort8 dv = *reinterpret_cast<const ushort8*>(ub + ch*136 + pxb + i*8);
            ushort8 vv = *reinterpret_cast<const ushort8*>(v + off + i*8);
            ushort8 ov;
            float rv[8];
            #pragma unroll
            for (int j=0;j<8;++j){
                rv[j] = u2f(dv[j]) + u2f(vv[j]);
                ov[j] = f2u(rv[j]);
            }
            *reinterpret_cast<ushort8*>(xout + off + i*8) = ov;
            if (xinit){
                float4v x0 = *reinterpret_cast<const float4v*>(xinit + off + i*8);
                float4v x1v = *reinterpret_cast<const float4v*>(xinit + off + i*8 + 4);
                ushort8 sv;
                sv[0]=f2u(rv[0]+x0.x); sv[1]=f2u(rv[1]+x0.y);
                sv[2]=f2u(rv[2]+x0.z); sv[3]=f2u(rv[3]+x0.w);
                sv[4]=f2u(rv[4]+x1v.x); sv[5]=f2u(rv[5]+x1v.y);
                sv[6]=f2u(rv[6]+x1v.z); sv[7]=f2u(rv[7]+x1v.w);
                *reinterpret_cast<ushort8*>(xsum + off + i*8) = sv;
            }
        }
    }
}

// ---------------------------------------------------------------- final conv (64->1, 3x3), 4 px/thread
__global__ __launch_bounds__(256) void k_final(
    const bf16* __restrict__ s, const float* __restrict__ w,
    const float* __restrict__ bias, float* __restrict__ out)
{
    int gid = blockIdx.x*256 + threadIdx.x;
    int b = gid >> 12;
    int sp4 = (gid & 4095) << 2;
    int y = sp4 >> 7, x0 = sp4 & 127;
    const bf16* sb = s + (size_t)b*CC*HWS;
    float acc[4];
    #pragma unroll
    for (int i=0;i<4;++i) acc[i] = bias[0];

    #pragma unroll 1
    for (int c=0;c<CC;++c){
        const bf16* ip = sb + (size_t)c*HWS;
        const float* wp = w + (size_t)c*9;
        #pragma unroll
        for (int ky=0;ky<3;++ky){
            int yy = y + ky - 1;
            float xv[6];
            if (yy >= 0 && yy < HH){
                const bf16* rp = ip + yy*WW + x0;
                ushort4v mv = *reinterpret_cast<const ushort4v*>(rp);
                xv[1]=u2f(mv[0]); xv[2]=u2f(mv[1]); xv[3]=u2f(mv[2]); xv[4]=u2f(mv[3]);
                xv[0] = (x0>0)    ? b2f(rp[-1]) : 0.f;
                xv[5] = (x0+4<WW) ? b2f(rp[4])  : 0.f;
            } else {
                #pragma unroll
                for (int i=0;i<6;++i) xv[i] = 0.f;
            }
            float w0 = wp[ky*3+0], w1 = wp[ky*3+1], w2 = wp[ky*3+2];
            #pragma unroll
            for (int i=0;i<4;++i)
                acc[i] = fmaf(w0, xv[i],
                         fmaf(w1, xv[i+1],
                         fmaf(w2, xv[i+2], acc[i])));
        }
    }
    float4v ov; ov.x=acc[0]; ov.y=acc[1]; ov.z=acc[2]; ov.w=acc[3];
    *reinterpret_cast<float4v*>(out + (size_t)gid*4) = ov;
}

// ---------------------------------------------------------------- launch
extern "C" void kernel_launch(void* const* d_in, const int* in_sizes, int n_in,
                              void* d_out, int out_size, void* d_ws, size_t ws_size,
                              hipStream_t stream)
{
    const float* x    = (const float*)d_in[0];
    const float* wz1  = (const float*)d_in[1];
    const float* bz1  = (const float*)d_in[2];
    const float* wz2  = (const float*)d_in[3];
    const float* bz2  = (const float*)d_in[4];
    const float* wf1  = (const float*)d_in[5];
    const float* bf1  = (const float*)d_in[6];
    const float* wf2  = (const float*)d_in[7];
    const float* bf2  = (const float*)d_in[8];
    const float* pw   = (const float*)d_in[9];
    const float* l1w  = (const float*)d_in[10];
    const float* l1b  = (const float*)d_in[11];
    const float* dww  = (const float*)d_in[12];
    const float* dwb  = (const float*)d_in[13];
    const float* l2w  = (const float*)d_in[14];
    const float* l2b  = (const float*)d_in[15];
    const float* ow   = (const float*)d_in[16];
    const float* obb  = (const float*)d_in[17];

    char* ws = (char*)d_ws;
    bf16* xc    = (bf16*)(ws);                    // 33,554,432 B
    bf16* v     = (bf16*)(ws + 33554432);         // 33,554,432 B
    bf16* x1    = (bf16*)(ws + 67108864);         //  8,388,608 B
    bf16* xsumb = (bf16*)(ws + 75497472);         // 33,554,432 B
    bf16* h1buf = (bf16*)(ws + 109051904);        // 67,108,864 B (total ~176 MB)

    for (int l=0;l<3;++l){
        if (l == 0)
            k_gate<1><<<512, 256, 0, stream>>>(x, nullptr,
                wz1 + l*CC*CC, bz1 + l*CC, wz2 + l*CC*CC, bz2 + l*CC,
                wf1 + l*CC*CC, bf1 + l*CC, wf2 + l*CC*CC, bf2 + l*CC, v);
        else
            k_gate<0><<<512, 256, 0, stream>>>(nullptr, xc,
                wz1 + l*CC*CC, bz1 + l*CC, wz2 + l*CC*CC, bz2 + l*CC,
                wf1 + l*CC*CC, bf1 + l*CC, wf2 + l*CC*CC, bf2 + l*CC, v);
        k_pconv<<<NPIX/(256*4), 256, 0, stream>>>(v, pw + l*DCC*DCC*9, x1);
        k_lin1h<<<NPIX/256, 256, 0, stream>>>(x1, v,
                l1w + l*CC*256, l1b + l*256, h1buf);
        k_dwA  <<<BB*HH, 256, 0, stream>>>(x1, v, h1buf,
                l1w + l*CC*256, l1b + l*256,
                dww + l*HIDN*9, dwb + l*HIDN,
                l2w + l*HIDN*CC, l2b + l*CC,
                xc, (l==2) ? x : nullptr, xsumb);
    }
    k_final<<<NPIX/(256*4), 256, 0, stream>>>(xsumb, ow, obb, (float*)d_out);
}

// Round 14
// 727.540 us; speedup vs baseline: 1.4290x; 1.0223x over previous
//
#include <hip/hip_runtime.h>
#include <hip/hip_bf16.h>

#define CC 64
#define HIDN 128
#define DCC 16
#define HH 128
#define WW 128
#define HWS (HH*WW)        // 16384
#define BB 16
#define NPIX (BB*HWS)      // 262144

typedef __hip_bfloat16 bf16;
typedef __attribute__((ext_vector_type(8))) unsigned short ushort8;
typedef __attribute__((ext_vector_type(4))) unsigned short ushort4v;
typedef __attribute__((ext_vector_type(4))) float float4v;
typedef __attribute__((ext_vector_type(8))) short bf16x8;
typedef __attribute__((ext_vector_type(4))) float f32x4;

__device__ __forceinline__ float rcp_fast(float x){ return __builtin_amdgcn_rcpf(x); }
__device__ __forceinline__ float ftanh(float x){
    float e = __expf(2.f*x);
    return 1.f - 2.f*rcp_fast(e + 1.f);
}
__device__ __forceinline__ float fsig(float x){
    return rcp_fast(1.f + __expf(-x));
}
__device__ __forceinline__ float fgelu(float x){
    return x * fsig(x*(1.5957691216f + 0.07135481283f*x*x));
}
__device__ __forceinline__ float b2f(bf16 v){ return __bfloat162float(v); }
__device__ __forceinline__ float u2f(unsigned short u){
    unsigned v = ((unsigned)u) << 16; return __uint_as_float(v);
}
__device__ __forceinline__ unsigned short f2u(float f){
    bf16 h = __float2bfloat16(f);
    return *reinterpret_cast<unsigned short*>(&h);
}
__device__ __forceinline__ bf16x8 packf(float4v a, float4v b){
    bf16x8 r;
    r[0]=(short)f2u(a.x); r[1]=(short)f2u(a.y); r[2]=(short)f2u(a.z); r[3]=(short)f2u(a.w);
    r[4]=(short)f2u(b.x); r[5]=(short)f2u(b.y); r[6]=(short)f2u(b.z); r[7]=(short)f2u(b.w);
    return r;
}

// ---------------------------------------------------------------- gate (MFMA, LDS-staged x, zero-shuffle chain)
template<int F32>
__global__ __launch_bounds__(256,2) void k_gate(
    const float* __restrict__ xf, const bf16* __restrict__ xb,
    const float* __restrict__ wz1, const float* __restrict__ bz1,
    const float* __restrict__ wz2, const float* __restrict__ bz2,
    const float* __restrict__ wf1, const float* __restrict__ bf1,
    const float* __restrict__ wf2, const float* __restrict__ bf2,
    bf16* __restrict__ vout)
{
    __shared__ __align__(16) unsigned short xs[512*64];   // 64 KB
    const int t = threadIdx.x;
    const int lane = t & 63;
    const int wv = t >> 6;
    const int col = lane & 15;
    const int g = lane >> 4;
    const int blk = blockIdx.x;
    const int b = blk >> 5;
    const int sp0 = (blk & 31) << 9;

    {
        const int ch = t & 63;
        const int wg = t >> 6;
        const size_t base = ((size_t)b*CC + ch)*HWS + sp0;
        #pragma unroll
        for (int i=0;i<16;++i){
            int bufpx = (wg*16 + i) << 3;
            ushort8 val;
            if (F32){
                float4v a = *reinterpret_cast<const float4v*>(xf + base + bufpx);
                float4v c = *reinterpret_cast<const float4v*>(xf + base + bufpx + 4);
                val[0]=f2u(a.x); val[1]=f2u(a.y); val[2]=f2u(a.z); val[3]=f2u(a.w);
                val[4]=f2u(c.x); val[5]=f2u(c.y); val[6]=f2u(c.z); val[7]=f2u(c.w);
            } else {
                val = *reinterpret_cast<const ushort8*>(xb + base + bufpx);
            }
            #pragma unroll
            for (int j=0;j<8;++j){
                int px = bufpx + j;
                *(unsigned short*)((char*)xs + px*128 + ((ch*2) ^ ((px&7)<<4))) = val[j];
            }
        }
    }

    bf16x8 Az1[4][2], Af1[4][2], Az2[4][2], Af2[4][2];
    #pragma unroll
    for (int ot=0; ot<4; ++ot){
        #pragma unroll
        for (int kh=0; kh<2; ++kh){
            const float* p;
            p = wz1 + (ot*16+col)*64 + kh*32 + g*8;
            Az1[ot][kh] = packf(*(const float4v*)p, *(const float4v*)(p+4));
            p = wf1 + (ot*16+col)*64 + kh*32 + g*8;
            Af1[ot][kh] = packf(*(const float4v*)p, *(const float4v*)(p+4));
            p = wz2 + (ot*16+col)*64 + kh*32 + g*4;
            Az2[ot][kh] = packf(*(const float4v*)p, *(const float4v*)(p+16));
            p = wf2 + (ot*16+col)*64 + kh*32 + g*4;
            Af2[ot][kh] = packf(*(const float4v*)p, *(const float4v*)(p+16));
        }
    }
    __syncthreads();

    bf16* vb = vout + (size_t)b*CC*HWS;

    for (int it = wv; it < 32; it += 4){
        const int lpx = it*16 + col;
        const int px = sp0 + lpx;
        bf16x8 Bx[2];
        Bx[0] = *(const bf16x8*)((char*)xs + lpx*128 + ((g*16) ^ ((lpx&7)<<4)));
        Bx[1] = *(const bf16x8*)((char*)xs + lpx*128 + ((64 + g*16) ^ ((lpx&7)<<4)));
        f32x4 Dz[4], Df[4];
        #pragma unroll
        for (int ot=0; ot<4; ++ot){
            Dz[ot] = *(const f32x4*)(bz1 + ot*16 + g*4);
            Df[ot] = *(const f32x4*)(bf1 + ot*16 + g*4);
        }
        #pragma unroll
        for (int kh=0; kh<2; ++kh)
            #pragma unroll
            for (int ot=0; ot<4; ++ot){
                Dz[ot] = __builtin_amdgcn_mfma_f32_16x16x32_bf16(Az1[ot][kh], Bx[kh], Dz[ot], 0,0,0);
                Df[ot] = __builtin_amdgcn_mfma_f32_16x16x32_bf16(Af1[ot][kh], Bx[kh], Df[ot], 0,0,0);
            }
        #pragma unroll
        for (int ot=0; ot<4; ++ot)
            #pragma unroll
            for (int r=0; r<4; ++r){
                Dz[ot][r] = ftanh(Dz[ot][r]);
                Df[ot][r] = ftanh(Df[ot][r]);
            }
        bf16x8 Bz[2], Bf[2];
        #pragma unroll
        for (int kh=0; kh<2; ++kh)
            #pragma unroll
            for (int j=0; j<4; ++j){
                Bz[kh][j]   = (short)f2u(Dz[2*kh][j]);
                Bz[kh][4+j] = (short)f2u(Dz[2*kh+1][j]);
                Bf[kh][j]   = (short)f2u(Df[2*kh][j]);
                Bf[kh][4+j] = (short)f2u(Df[2*kh+1][j]);
            }
        f32x4 Ez[4], Ef[4];
        #pragma unroll
        for (int ot=0; ot<4; ++ot){
            Ez[ot] = *(const f32x4*)(bz2 + ot*16 + g*4);
            Ef[ot] = *(const f32x4*)(bf2 + ot*16 + g*4);
        }
        #pragma unroll
        for (int kh=0; kh<2; ++kh)
            #pragma unroll
            for (int ot=0; ot<4; ++ot){
                Ez[ot] = __builtin_amdgcn_mfma_f32_16x16x32_bf16(Az2[ot][kh], Bz[kh], Ez[ot], 0,0,0);
                Ef[ot] = __builtin_amdgcn_mfma_f32_16x16x32_bf16(Af2[ot][kh], Bf[kh], Ef[ot], 0,0,0);
            }
        #pragma unroll
        for (int ot=0; ot<4; ++ot)
            #pragma unroll
            for (int r=0; r<4; ++r){
                float Zv = ftanh(Ez[ot][r]);
                float Fv = fsig(Ef[ot][r]);
                *reinterpret_cast<unsigned short*>(vb + (size_t)(ot*16+g*4+r)*HWS + px)
                    = f2u((1.f - Fv)*Zv);
            }
    }
}

// ---------------------------------------------------------------- pconv (16->16, 3x3), 4 px/thread, XCD-swizzled
__global__ __launch_bounds__(256) void k_pconv(
    const bf16* __restrict__ v, const float* __restrict__ w, bf16* __restrict__ x1)
{
    int blk0 = blockIdx.x;                        // 256 blocks
    int blk = (blk0 & 7)*32 + (blk0 >> 3);        // XCD-contiguous
    int gid = blk*256 + threadIdx.x;
    int b = gid >> 12;
    int sp4 = (gid & 4095) << 2;
    int y = sp4 >> 7, x0 = sp4 & 127;
    const bf16* vb = v + (size_t)b*CC*HWS;
    float acc[DCC][4];
    #pragma unroll
    for (int o=0;o<DCC;++o)
        #pragma unroll
        for (int i=0;i<4;++i) acc[o][i] = 0.f;

    #pragma unroll 1
    for (int ic=0; ic<DCC; ++ic){
        const bf16* ip = vb + (size_t)ic*HWS;
        float xv[3][6];
        #pragma unroll
        for (int ky=0;ky<3;++ky){
            int yy = y + ky - 1;
            if (yy >= 0 && yy < HH){
                const bf16* rp = ip + yy*WW + x0;
                ushort4v mv = *reinterpret_cast<const ushort4v*>(rp);
                xv[ky][1]=u2f(mv[0]); xv[ky][2]=u2f(mv[1]);
                xv[ky][3]=u2f(mv[2]); xv[ky][4]=u2f(mv[3]);
                xv[ky][0] = (x0>0)     ? b2f(rp[-1]) : 0.f;
                xv[ky][5] = (x0+4<WW)  ? b2f(rp[4])  : 0.f;
            } else {
                #pragma unroll
                for (int i=0;i<6;++i) xv[ky][i] = 0.f;
            }
        }
        #pragma unroll
        for (int o=0;o<DCC;++o){
            const float* wp = w + (size_t)(o*DCC+ic)*9;
            #pragma unroll
            for (int ky=0;ky<3;++ky){
                float w0 = wp[ky*3+0], w1 = wp[ky*3+1], w2 = wp[ky*3+2];
                #pragma unroll
                for (int i=0;i<4;++i)
                    acc[o][i] = fmaf(w0, xv[ky][i],
                                fmaf(w1, xv[ky][i+1],
                                fmaf(w2, xv[ky][i+2], acc[o][i])));
            }
        }
    }
    bf16* xo = x1 + (size_t)b*DCC*HWS + sp4;
    #pragma unroll
    for (int o=0;o<DCC;++o){
        ushort4v ov;
        #pragma unroll
        for (int i=0;i<4;++i) ov[i] = f2u(acc[o][i]);
        *reinterpret_cast<ushort4v*>(xo + (size_t)o*HWS) = ov;
    }
}

// ---------------------------------------------------------------- lin1h: h1 = gelu(lin1_h(xcat)), computed ONCE per px.
__global__ __launch_bounds__(256) void k_lin1h(
    const bf16* __restrict__ x1, const bf16* __restrict__ v,
    const float* __restrict__ l1w, const float* __restrict__ l1b,
    bf16* __restrict__ h1out)
{
    __shared__ __align__(16) unsigned short xs[256*64];   // 32 KB
    __shared__ __align__(16) unsigned short tr[4][32*66]; // 16.5 KB, wave-private
    const int t = threadIdx.x;
    const int lane = t & 63;
    const int wv = t >> 6;
    const int col = lane & 15;
    const int g = lane >> 4;
    const int blk = blockIdx.x;         // 1024 blocks
    const int b = blk >> 6;
    const int sp0 = (blk & 63) << 8;

    {
        const int ch = t & 63;
        const int wg = t >> 6;
        const bf16* src = (ch < DCC) ? x1 + ((size_t)b*DCC + ch)*HWS
                                     : v  + ((size_t)b*CC  + ch)*HWS;
        #pragma unroll
        for (int i=0;i<8;++i){
            int bufpx = (wg*8 + i) << 3;
            ushort8 val = *reinterpret_cast<const ushort8*>(src + sp0 + bufpx);
            #pragma unroll
            for (int j=0;j<8;++j){
                int px = bufpx + j;
                *(unsigned short*)((char*)xs + px*128 + ((ch*2) ^ ((px&7)<<4))) = val[j];
            }
        }
    }
    __syncthreads();

    unsigned short* trw = &tr[wv][0];
    const int lpx0 = wv*64;

    #pragma unroll 1
    for (int oc=0; oc<4; ++oc){
        bf16x8 A1[2][2];
        #pragma unroll
        for (int t2=0;t2<2;++t2)
            #pragma unroll
            for (int kh=0;kh<2;++kh){
                bf16x8 fa;
                #pragma unroll
                for (int j=0;j<8;++j){
                    int cin = kh*32 + g*8 + j;
                    fa[j] = (short)f2u(l1w[cin*256 + oc*32 + t2*16 + col]);
                }
                A1[t2][kh]=fa;
            }
        #pragma unroll
        for (int lt=0;lt<4;++lt){
            int px = lpx0 + lt*16 + col;
            bf16x8 B0 = *(const bf16x8*)((char*)xs + px*128 + ((g*16) ^ ((px&7)<<4)));
            bf16x8 B1 = *(const bf16x8*)((char*)xs + px*128 + ((64 + g*16) ^ ((px&7)<<4)));
            f32x4 D0 = *(const f32x4*)(l1b + oc*32 + g*4);
            f32x4 D1 = *(const f32x4*)(l1b + oc*32 + 16 + g*4);
            D0 = __builtin_amdgcn_mfma_f32_16x16x32_bf16(A1[0][0], B0, D0, 0,0,0);
            D0 = __builtin_amdgcn_mfma_f32_16x16x32_bf16(A1[0][1], B1, D0, 0,0,0);
            D1 = __builtin_amdgcn_mfma_f32_16x16x32_bf16(A1[1][0], B0, D1, 0,0,0);
            D1 = __builtin_amdgcn_mfma_f32_16x16x32_bf16(A1[1][1], B1, D1, 0,0,0);
            int lp = lt*16 + col;
            #pragma unroll
            for (int rr=0;rr<4;++rr){
                trw[(g*4+rr)*66 + lp]    = f2u(fgelu(D0[rr]));
                trw[(16+g*4+rr)*66 + lp] = f2u(fgelu(D1[rr]));
            }
        }
        {
            int ch2 = lane >> 1;
            int half = lane & 1;
            const unsigned short* srcp = trw + ch2*66 + half*32;
            bf16* dst = h1out + ((size_t)(b*HIDN + oc*32 + ch2))*HWS + sp0 + lpx0 + half*32;
            #pragma unroll
            for (int i=0;i<4;++i){
                ushort8 u8 = *reinterpret_cast<const ushort8*>(srcp + i*8);
                *reinterpret_cast<ushort8*>(dst + i*8) = u8;
            }
        }
    }
}

// ---------------------------------------------------------------- wprep: per-layer weight fragments, packed per-lane
// buf1 [cc][t2][kh][lane][8] bf16 (h2-half of l1w); buf2 [cc][ot][lane][8] bf16 (w2).
// One block per layer.
__global__ __launch_bounds__(256) void k_wprep(
    const float* __restrict__ l1w_all, const float* __restrict__ w2_all,
    bf16* __restrict__ frag_all)
{
    const int l = blockIdx.x;
    const float* l1w = l1w_all + (size_t)l*CC*256;
    const float* w2  = w2_all  + (size_t)l*HIDN*CC;
    unsigned short* buf1 = (unsigned short*)(frag_all + (size_t)l*16384);
    unsigned short* buf2 = buf1 + 8192;
    const int t = threadIdx.x;
    const int lane = t & 63;
    const int col = lane & 15;
    const int g = lane >> 4;
    #pragma unroll
    for (int c4=0;c4<4;++c4){
        int combo = (t>>6)*4 + c4;          // 0..15
        {   // buf1: combo = (cc*2+t2)*2+kh
            int cc = combo >> 2, t2 = (combo>>1)&1, kh = combo&1;
            #pragma unroll
            for (int j=0;j<8;++j){
                int cin = kh*32 + g*8 + j;
                buf1[(combo*64 + lane)*8 + j] =
                    f2u(l1w[cin*256 + 128 + cc*32 + t2*16 + col]);
            }
        }
        {   // buf2: combo = cc*4+ot
            int cc = combo >> 2, ot = combo & 3;
            #pragma unroll
            for (int j=0;j<8;++j){
                int k = cc*32 + ((j>>2)<<4) + (g<<2) + (j&3);
                buf2[(combo*64 + lane)*8 + j] = f2u(w2[k*64 + ot*16 + col]);
            }
        }
    }
}

// ---------------------------------------------------------------- dwA: dwconv(h1)+gelu + lazy-h2 + gate + lin2 fused
// R14: weight fragments pre-packed per-lane in global (k_wprep, L2-resident 32 KB)
// -> no per-block weight staging, LDS 34 KB -> 4 blocks/CU (R13 post-mortem:
// 68 KB LDS capped occupancy at 20% and staging caused 2.6M bank conflicts).
__global__ __launch_bounds__(256) void k_dwA(
    const bf16* __restrict__ x1, const bf16* __restrict__ v,
    const bf16* __restrict__ h1, const bf16* __restrict__ wfrag,
    const float* __restrict__ l1b,
    const float* __restrict__ dww, const float* __restrict__ dwb,
    const float* __restrict__ l2b,
    bf16* __restrict__ xout,
    const float* __restrict__ xinit,   // non-null on last layer
    bf16* __restrict__ xsum)
{
    __shared__ __align__(16) unsigned short xs[128*64];    // 16 KB (center row)
    __shared__ __align__(16) unsigned short ub[64*136];    // 17 KB (u chunks / epilogue transpose)
    const int t = threadIdx.x;
    const int lane = t & 63;
    const int wv = t >> 6;
    const int col = lane & 15;
    const int g = lane >> 4;
    const int blk0 = blockIdx.x;          // 2048 blocks
    const int blk = (blk0 & 7)*256 + (blk0 >> 3);   // XCD-contiguous rows
    const int b = blk >> 7;
    const int y = blk & 127;

    const int cj  = (t>>3) & 31;     // dw channel within chunk
    const int pxo = (t & 7) << 4;    // dw 16-px group

    const unsigned short* buf1 = (const unsigned short*)wfrag;
    const unsigned short* buf2 = buf1 + 8192;

    // ---- prefetch state (chunk-ahead registers)
    ushort8 pfa[3], pfb[3];
    unsigned short pfl[3], pfr[3];
    float pw9[9], pbj;
    auto LOADCHUNK = [&](int cc){
        int chg = cc*32 + cj;
        const bf16* h1p = h1 + ((size_t)(b*HIDN + chg))*HWS;
        #pragma unroll
        for (int ky=0; ky<3; ++ky){
            int gy = y + ky - 1;
            if (gy >= 0 && gy < HH){
                const bf16* rp = h1p + (size_t)gy*WW + pxo;
                pfa[ky] = *reinterpret_cast<const ushort8*>(rp);
                pfb[ky] = *reinterpret_cast<const ushort8*>(rp+8);
                pfl[ky] = (pxo>0)     ? *reinterpret_cast<const unsigned short*>(rp-1)  : 0;
                pfr[ky] = (pxo+16<WW) ? *reinterpret_cast<const unsigned short*>(rp+16) : 0;
            } else {
                #pragma unroll
                for (int i=0;i<8;++i){ pfa[ky][i]=0; pfb[ky][i]=0; }
                pfl[ky]=0; pfr[ky]=0;
            }
        }
        #pragma unroll
        for (int i=0;i<9;++i) pw9[i] = dww[chg*9+i];
        pbj = dwb[chg];
    };

    LOADCHUNK(0);   // earliest issue

    {   // stage x-cat center row: 64ch x 128px
        const int ch = t & 63;
        const int wg = t >> 6;
        const bf16* src = (ch < DCC) ? x1 + ((size_t)b*DCC + ch)*HWS
                                     : v  + ((size_t)b*CC  + ch)*HWS;
        #pragma unroll
        for (int i=0;i<2;++i){
            int bufpx = (wg*2 + i) << 3;
            ushort8 val = *reinterpret_cast<const ushort8*>(src + (size_t)y*WW + bufpx);
            #pragma unroll
            for (int j=0;j<8;++j){
                int px = bufpx + j;
                *(unsigned short*)((char*)xs + px*128 + ((ch*2) ^ ((px&7)<<4))) = val[j];
            }
        }
    }
    __syncthreads();

    f32x4 Dx[2][4];
    #pragma unroll
    for (int q=0;q<2;++q)
        #pragma unroll
        for (int ot=0;ot<4;++ot)
            Dx[q][ot] = *(const f32x4*)(l2b + ot*16 + g*4);

    #pragma unroll 1
    for (int cc=0; cc<4; ++cc){
        // ---- dw conv from prefetched regs -> u
        ushort8 o0v, o1v;
        {
            float acc[16];
            #pragma unroll
            for (int i=0;i<16;++i) acc[i]=0.f;
            #pragma unroll
            for (int ky=0; ky<3; ++ky){
                float m[16];
                #pragma unroll
                for (int i=0;i<8;++i){ m[i]=u2f(pfa[ky][i]); m[8+i]=u2f(pfb[ky][i]); }
                float lf = u2f(pfl[ky]);
                float rt = u2f(pfr[ky]);
                float w0=pw9[ky*3], w1=pw9[ky*3+1], wv2=pw9[ky*3+2];
                #pragma unroll
                for (int i=0;i<16;++i){
                    float l  = i ? m[i-1] : lf;
                    float r_ = (i==15) ? rt : m[i+1];
                    acc[i] = fmaf(w0,l, fmaf(w1,m[i], fmaf(wv2,r_,acc[i])));
                }
            }
            #pragma unroll
            for (int i=0;i<8;++i){
                o0v[i] = f2u(fgelu(acc[i]+pbj));
                o1v[i] = f2u(fgelu(acc[8+i]+pbj));
            }
        }
        // issue next chunk's loads now (in flight across barrier + MFMA phase)
        if (cc < 3) LOADCHUNK(cc+1);
        *(ushort8*)(ub + cj*260 + pxo)     = o0v;
        *(ushort8*)(ub + cj*260 + pxo + 8) = o1v;
        __syncthreads();
        // ---- fused: lazy h2 MFMA + gate (in-reg) + lin2 MFMA; frags from L2
        {
            bf16x8 A1g[2][2];
            #pragma unroll
            for (int t2=0;t2<2;++t2)
                #pragma unroll
                for (int kh=0;kh<2;++kh){
                    int combo = (cc*2+t2)*2+kh;
                    ushort8 u = *reinterpret_cast<const ushort8*>(buf1 + (combo*64 + lane)*8);
                    bf16x8 f;
                    #pragma unroll
                    for (int j=0;j<8;++j) f[j]=(short)u[j];
                    A1g[t2][kh]=f;
                }
            bf16x8 A2[4];
            #pragma unroll
            for (int ot=0;ot<4;++ot){
                int combo = cc*4+ot;
                ushort8 u = *reinterpret_cast<const ushort8*>(buf2 + (combo*64 + lane)*8);
                bf16x8 f;
                #pragma unroll
                for (int j=0;j<8;++j) f[j]=(short)u[j];
                A2[ot] = f;
            }
            #pragma unroll
            for (int q=0;q<2;++q){
                int px = (wv*2+q)*16 + col;
                bf16x8 B0 = *(const bf16x8*)((char*)xs + px*128 + ((g*16) ^ ((px&7)<<4)));
                bf16x8 B1 = *(const bf16x8*)((char*)xs + px*128 + ((64 + g*16) ^ ((px&7)<<4)));
                f32x4 D0 = *(const f32x4*)(l1b + 128 + cc*32 + g*4);
                f32x4 D1 = *(const f32x4*)(l1b + 128 + cc*32 + 16 + g*4);
                D0 = __builtin_amdgcn_mfma_f32_16x16x32_bf16(A1g[0][0], B0, D0, 0,0,0);
                D0 = __builtin_amdgcn_mfma_f32_16x16x32_bf16(A1g[0][1], B1, D0, 0,0,0);
                D1 = __builtin_amdgcn_mfma_f32_16x16x32_bf16(A1g[1][0], B0, D1, 0,0,0);
                D1 = __builtin_amdgcn_mfma_f32_16x16x32_bf16(A1g[1][1], B1, D1, 0,0,0);
                bf16x8 Bg;
                #pragma unroll
                for (int j=0;j<4;++j){
                    float u0 = u2f(ub[(g*4+j)*260 + px]);
                    float u1 = u2f(ub[(16+g*4+j)*260 + px]);
                    Bg[j]   = (short)f2u(u0 * fgelu(D0[j]));
                    Bg[4+j] = (short)f2u(u1 * fgelu(D1[j]));
                }
                #pragma unroll
                for (int ot=0;ot<4;++ot)
                    Dx[q][ot] = __builtin_amdgcn_mfma_f32_16x16x32_bf16(A2[ot], Bg, Dx[q][ot], 0,0,0);
            }
        }
        __syncthreads();
    }
    // ---- epilogue: transpose Dx through ub, then coalesced writes
    #pragma unroll
    for (int q=0;q<2;++q)
        #pragma unroll
        for (int ot=0;ot<4;++ot)
            #pragma unroll
            for (int rr=0;rr<4;++rr)
                ub[(ot*16 + g*4 + rr)*136 + (wv*2+q)*16 + col] = f2u(Dx[q][ot][rr]);
    __syncthreads();
    {
        int ch  = t >> 2;
        int pxb = (t & 3) * 32;
        size_t off = ((size_t)(b*CC + ch))*HWS + (size_t)y*WW + pxb;
        #pragma unroll
        for (int i=0;i<4;++i){
            ushort8 dv = *reinterpret_cast<const ushort8*>(ub + ch*136 + pxb + i*8);
            ushort8 vv = *reinterpret_cast<const ushort8*>(v + off + i*8);
            ushort8 ov;
            float rv[8];
            #pragma unroll
            for (int j=0;j<8;++j){
                rv[j] = u2f(dv[j]) + u2f(vv[j]);
                ov[j] = f2u(rv[j]);
            }
            *reinterpret_cast<ushort8*>(xout + off + i*8) = ov;
            if (xinit){
                float4v x0 = *reinterpret_cast<const float4v*>(xinit + off + i*8);
                float4v x1v = *reinterpret_cast<const float4v*>(xinit + off + i*8 + 4);
                ushort8 sv;
                sv[0]=f2u(rv[0]+x0.x); sv[1]=f2u(rv[1]+x0.y);
                sv[2]=f2u(rv[2]+x0.z); sv[3]=f2u(rv[3]+x0.w);
                sv[4]=f2u(rv[4]+x1v.x); sv[5]=f2u(rv[5]+x1v.y);
                sv[6]=f2u(rv[6]+x1v.z); sv[7]=f2u(rv[7]+x1v.w);
                *reinterpret_cast<ushort8*>(xsum + off + i*8) = sv;
            }
        }
    }
}

// ---------------------------------------------------------------- final conv (64->1, 3x3), 4 px/thread
__global__ __launch_bounds__(256) void k_final(
    const bf16* __restrict__ s, const float* __restrict__ w,
    const float* __restrict__ bias, float* __restrict__ out)
{
    int gid = blockIdx.x*256 + threadIdx.x;
    int b = gid >> 12;
    int sp4 = (gid & 4095) << 2;
    int y = sp4 >> 7, x0 = sp4 & 127;
    const bf16* sb = s + (size_t)b*CC*HWS;
    float acc[4];
    #pragma unroll
    for (int i=0;i<4;++i) acc[i] = bias[0];

    #pragma unroll 1
    for (int c=0;c<CC;++c){
        const bf16* ip = sb + (size_t)c*HWS;
        const float* wp = w + (size_t)c*9;
        #pragma unroll
        for (int ky=0;ky<3;++ky){
            int yy = y + ky - 1;
            float xv[6];
            if (yy >= 0 && yy < HH){
                const bf16* rp = ip + yy*WW + x0;
                ushort4v mv = *reinterpret_cast<const ushort4v*>(rp);
                xv[1]=u2f(mv[0]); xv[2]=u2f(mv[1]); xv[3]=u2f(mv[2]); xv[4]=u2f(mv[3]);
                xv[0] = (x0>0)    ? b2f(rp[-1]) : 0.f;
                xv[5] = (x0+4<WW) ? b2f(rp[4])  : 0.f;
            } else {
                #pragma unroll
                for (int i=0;i<6;++i) xv[i] = 0.f;
            }
            float w0 = wp[ky*3+0], w1 = wp[ky*3+1], w2 = wp[ky*3+2];
            #pragma unroll
            for (int i=0;i<4;++i)
                acc[i] = fmaf(w0, xv[i],
                         fmaf(w1, xv[i+1],
                         fmaf(w2, xv[i+2], acc[i])));
        }
    }
    float4v ov; ov.x=acc[0]; ov.y=acc[1]; ov.z=acc[2]; ov.w=acc[3];
    *reinterpret_cast<float4v*>(out + (size_t)gid*4) = ov;
}

// ---------------------------------------------------------------- launch
extern "C" void kernel_launch(void* const* d_in, const int* in_sizes, int n_in,
                              void* d_out, int out_size, void* d_ws, size_t ws_size,
                              hipStream_t stream)
{
    const float* x    = (const float*)d_in[0];
    const float* wz1  = (const float*)d_in[1];
    const float* bz1  = (const float*)d_in[2];
    const float* wz2  = (const float*)d_in[3];
    const float* bz2  = (const float*)d_in[4];
    const float* wf1  = (const float*)d_in[5];
    const float* bf1  = (const float*)d_in[6];
    const float* wf2  = (const float*)d_in[7];
    const float* bf2  = (const float*)d_in[8];
    const float* pw   = (const float*)d_in[9];
    const float* l1w  = (const float*)d_in[10];
    const float* l1b  = (const float*)d_in[11];
    const float* dww  = (const float*)d_in[12];
    const float* dwb  = (const float*)d_in[13];
    const float* l2w  = (const float*)d_in[14];
    const float* l2b  = (const float*)d_in[15];
    const float* ow   = (const float*)d_in[16];
    const float* obb  = (const float*)d_in[17];

    char* ws = (char*)d_ws;
    bf16* xc    = (bf16*)(ws);                    // 33,554,432 B
    bf16* v     = (bf16*)(ws + 33554432);         // 33,554,432 B
    bf16* x1    = (bf16*)(ws + 67108864);         //  8,388,608 B
    bf16* xsumb = (bf16*)(ws + 75497472);         // 33,554,432 B
    bf16* h1buf = (bf16*)(ws + 109051904);        // 67,108,864 B
    bf16* wfrag = (bf16*)(ws + 176160768);        // 3 x 32 KB

    k_wprep<<<3, 256, 0, stream>>>(l1w, l2w, wfrag);
    for (int l=0;l<3;++l){
        if (l == 0)
            k_gate<1><<<512, 256, 0, stream>>>(x, nullptr,
                wz1 + l*CC*CC, bz1 + l*CC, wz2 + l*CC*CC, bz2 + l*CC,
                wf1 + l*CC*CC, bf1 + l*CC, wf2 + l*CC*CC, bf2 + l*CC, v);
        else
            k_gate<0><<<512, 256, 0, stream>>>(nullptr, xc,
                wz1 + l*CC*CC, bz1 + l*CC, wz2 + l*CC*CC, bz2 + l*CC,
                wf1 + l*CC*CC, bf1 + l*CC, wf2 + l*CC*CC, bf2 + l*CC, v);
        k_pconv<<<NPIX/(256*4), 256, 0, stream>>>(v, pw + l*DCC*DCC*9, x1);
        k_lin1h<<<NPIX/256, 256, 0, stream>>>(x1, v,
                l1w + l*CC*256, l1b + l*256, h1buf);
        k_dwA  <<<BB*HH, 256, 0, stream>>>(x1, v, h1buf, wfrag + (size_t)l*16384,
                l1b + l*256,
                dww + l*HIDN*9, dwb + l*HIDN,
                l2b + l*CC,
                xc, (l==2) ? x : nullptr, xsumb);
    }
    k_final<<<NPIX/(256*4), 256, 0, stream>>>(xsumb, ow, obb, (float*)d_out);
}